// Round 1
// baseline (1120.805 us; speedup 1.0000x reference)
//
#include <hip/hip_runtime.h>
#include <hip/hip_bf16.h>

#define TPB 256
#define SCAN_TILE 1024

// ---------------- preprocessing kernels ----------------

__global__ void count_kernel(const int* __restrict__ dst, int E, int* __restrict__ cnt) {
    int e = blockIdx.x * TPB + threadIdx.x;
    if (e < E) atomicAdd(&cnt[dst[e]], 1);
}

__global__ void dinv_kernel(const int* __restrict__ cnt, float* __restrict__ dinv, int n) {
    int i = blockIdx.x * TPB + threadIdx.x;
    if (i < n) dinv[i] = rsqrtf((float)(cnt[i] + 1));   // +1 self-loop
}

__global__ void scan_reduce(const int* __restrict__ cnt, int* __restrict__ part, int n) {
    __shared__ int sdata[TPB];
    int base = blockIdx.x * SCAN_TILE;
    int t = threadIdx.x;
    int s = 0;
    for (int j = t; j < SCAN_TILE; j += TPB) {
        int i = base + j;
        s += (i < n) ? cnt[i] : 0;
    }
    sdata[t] = s; __syncthreads();
    for (int off = TPB / 2; off > 0; off >>= 1) {
        if (t < off) sdata[t] += sdata[t + off];
        __syncthreads();
    }
    if (t == 0) part[blockIdx.x] = sdata[0];
}

// single block, 512 threads: exclusive scan of part[0..nb), write total to *rowN
__global__ void scan_part(int* __restrict__ part, int nb, int* __restrict__ rowN) {
    __shared__ int sdata[512];
    int t = threadIdx.x;
    int v = (t < nb) ? part[t] : 0;
    sdata[t] = v; __syncthreads();
    for (int off = 1; off < 512; off <<= 1) {
        int xv = (t >= off) ? sdata[t - off] : 0;
        __syncthreads();
        sdata[t] += xv;
        __syncthreads();
    }
    if (t < nb) part[t] = sdata[t] - v;      // exclusive
    if (t == 511) *rowN = sdata[511];        // total = E
}

__global__ void scan_write(const int* __restrict__ cnt, const int* __restrict__ part,
                           int* __restrict__ row, int n) {
    __shared__ int sdata[TPB];
    int t = threadIdx.x;
    int base = blockIdx.x * SCAN_TILE;
    int idx0 = base + t * 4;
    int v[4]; int local = 0;
#pragma unroll
    for (int j = 0; j < 4; j++) {
        int i = idx0 + j;
        v[j] = (i < n) ? cnt[i] : 0;
        local += v[j];
    }
    sdata[t] = local; __syncthreads();
    for (int off = 1; off < TPB; off <<= 1) {
        int xv = (t >= off) ? sdata[t - off] : 0;
        __syncthreads();
        sdata[t] += xv;
        __syncthreads();
    }
    int excl = sdata[t] - local + part[blockIdx.x];
#pragma unroll
    for (int j = 0; j < 4; j++) {
        int i = idx0 + j;
        if (i < n) { row[i] = excl; excl += v[j]; }
    }
}

__global__ void scatter_kernel(const int* __restrict__ src, const int* __restrict__ dst, int E,
                               const float* __restrict__ dinv, const int* __restrict__ row,
                               int* __restrict__ cursor, int2* __restrict__ edges) {
    int e = blockIdx.x * TPB + threadIdx.x;
    if (e >= E) return;
    int s = src[e], d = dst[e];
    int pos = row[d] + atomicAdd(&cursor[d], 1);
    int2 p;
    p.x = s;
    p.y = __float_as_int(dinv[s]);
    edges[pos] = p;
}

// ---------------- GEMM: Hout[n,128] = X[n,128] @ W[128,128] ----------------
// 64 rows per block, 256 threads, each thread computes 4 rows x 8 cols.
// Dynamic LDS: xT[128][64] (32KB) + W[128][128] (64KB) = 96KB.

#define TM 64

__global__ __launch_bounds__(256) void gemm_kernel(const float* __restrict__ X,
                                                   const float* __restrict__ W,
                                                   float* __restrict__ Hout, int n) {
    extern __shared__ float smem[];
    float* xT = smem;                // [k][r] : k*64 + r
    float* Wl = smem + 128 * TM;     // [k][c] : k*128 + c

    int t = threadIdx.x;
    int row0 = blockIdx.x * TM;

    // stage W (16384 floats)
    {
        const float4* Wv = (const float4*)W;
        float4* Wlv = (float4*)Wl;
        for (int j = t; j < 16384 / 4; j += 256) Wlv[j] = Wv[j];
    }
    // stage X transposed
    {
        for (int j = t; j < TM * 32; j += 256) {
            int r = j >> 5;      // row within tile
            int kq = j & 31;     // float4 index along k
            int grow = row0 + r;
            float4 v = (grow < n) ? ((const float4*)X)[(size_t)grow * 32 + kq]
                                  : make_float4(0.f, 0.f, 0.f, 0.f);
            xT[(kq * 4 + 0) * TM + r] = v.x;
            xT[(kq * 4 + 1) * TM + r] = v.y;
            xT[(kq * 4 + 2) * TM + r] = v.z;
            xT[(kq * 4 + 3) * TM + r] = v.w;
        }
    }
    __syncthreads();

    int tx = t & 15;   // col group: cols tx*8..tx*8+7
    int ty = t >> 4;   // row group: rows ty*4..ty*4+3

    float acc[4][8];
#pragma unroll
    for (int r = 0; r < 4; r++)
#pragma unroll
        for (int c = 0; c < 8; c++) acc[r][c] = 0.f;

#pragma unroll 4
    for (int k = 0; k < 128; k++) {
        float4 a  = *(const float4*)&xT[k * TM + ty * 4];
        float4 w0 = *(const float4*)&Wl[k * 128 + tx * 8];
        float4 w1 = *(const float4*)&Wl[k * 128 + tx * 8 + 4];
        float av[4] = {a.x, a.y, a.z, a.w};
        float wv[8] = {w0.x, w0.y, w0.z, w0.w, w1.x, w1.y, w1.z, w1.w};
#pragma unroll
        for (int r = 0; r < 4; r++)
#pragma unroll
            for (int c = 0; c < 8; c++) acc[r][c] += av[r] * wv[c];
    }

#pragma unroll
    for (int r = 0; r < 4; r++) {
        int grow = row0 + ty * 4 + r;
        if (grow < n) {
            float4* o = (float4*)&Hout[(size_t)grow * 128 + tx * 8];
            o[0] = make_float4(acc[r][0], acc[r][1], acc[r][2], acc[r][3]);
            o[1] = make_float4(acc[r][4], acc[r][5], acc[r][6], acc[r][7]);
        }
    }
}

// ---------------- aggregation: out[i] = relu( sum_{e in N(i)} w_e * h[src_e] + dinv_i^2 h[i] + b )
// one block (128 threads) per node, thread = feature.

__global__ __launch_bounds__(128) void agg_kernel(const float* __restrict__ h,
                                                  const float* __restrict__ dinv,
                                                  const int* __restrict__ row,
                                                  const int2* __restrict__ edges,
                                                  const float* __restrict__ bias,
                                                  float* __restrict__ out, int n) {
    int i = blockIdx.x;
    int f = threadIdx.x;
    float di = dinv[i];
    float acc = di * di * h[(size_t)i * 128 + f];   // self-loop
    int e0 = row[i], e1 = row[i + 1];

    int e = e0;
    int2 pn = (e < e1) ? edges[e] : make_int2(0, 0);
    while (e < e1) {
        int2 p = pn;
        ++e;
        if (e < e1) pn = edges[e];
        float w = __int_as_float(p.y) * di;
        acc += w * h[(size_t)p.x * 128 + f];
    }
    out[(size_t)i * 128 + f] = fmaxf(acc + bias[f], 0.f);
}

// ---------------- launch ----------------

extern "C" void kernel_launch(void* const* d_in, const int* in_sizes, int n_in,
                              void* d_out, int out_size, void* d_ws, size_t ws_size,
                              hipStream_t stream) {
    const float* x  = (const float*)d_in[0];
    const int*   ei = (const int*)d_in[1];
    const float* W0 = (const float*)d_in[2];
    const float* b0 = (const float*)d_in[3];
    const float* W1 = (const float*)d_in[4];
    const float* b1 = (const float*)d_in[5];
    const float* W2 = (const float*)d_in[6];
    const float* b2 = (const float*)d_in[7];

    const int H = 128;
    int n = in_sizes[0] / H;
    int E = in_sizes[1] / 2;
    const int* srcp = ei;
    const int* dstp = ei + E;

    // workspace bump allocator
    char* p = (char*)d_ws;
    auto alloc = [&](size_t bytes) {
        void* r = (void*)p;
        p += (bytes + 255) & ~(size_t)255;
        return r;
    };
    float* bufA  = (float*)alloc((size_t)n * H * sizeof(float));   // 51.2 MB
    int*  cnt    = (int*)alloc((size_t)n * sizeof(int));
    int*  cursor = (int*)alloc((size_t)n * sizeof(int));
    float* dinv  = (float*)alloc((size_t)n * sizeof(float));
    int*  row    = (int*)alloc((size_t)(n + 1) * sizeof(int));
    int*  part   = (int*)alloc(512 * sizeof(int));
    int2* edges  = (int2*)alloc((size_t)E * sizeof(int2));         // 12.8 MB

    hipMemsetAsync(cnt, 0, (size_t)n * sizeof(int), stream);
    hipMemsetAsync(cursor, 0, (size_t)n * sizeof(int), stream);

    count_kernel<<<(E + TPB - 1) / TPB, TPB, 0, stream>>>(dstp, E, cnt);
    dinv_kernel<<<(n + TPB - 1) / TPB, TPB, 0, stream>>>(cnt, dinv, n);

    int nb = (n + SCAN_TILE - 1) / SCAN_TILE;
    scan_reduce<<<nb, TPB, 0, stream>>>(cnt, part, n);
    scan_part<<<1, 512, 0, stream>>>(part, nb, &row[n]);
    scan_write<<<nb, TPB, 0, stream>>>(cnt, part, row, n);
    scatter_kernel<<<(E + TPB - 1) / TPB, TPB, 0, stream>>>(srcp, dstp, E, dinv, row, cursor, edges);

    float* out = (float*)d_out;
    size_t lds = (size_t)(128 * TM + 128 * 128) * sizeof(float);   // 96 KB
    int gemm_blocks = (n + TM - 1) / TM;

    // layer 0: x -> bufA -> out
    gemm_kernel<<<gemm_blocks, 256, lds, stream>>>(x, W0, bufA, n);
    agg_kernel<<<n, 128, 0, stream>>>(bufA, dinv, row, edges, b0, out, n);
    // layer 1: out -> bufA -> out
    gemm_kernel<<<gemm_blocks, 256, lds, stream>>>(out, W1, bufA, n);
    agg_kernel<<<n, 128, 0, stream>>>(bufA, dinv, row, edges, b1, out, n);
    // layer 2: out -> bufA -> out
    gemm_kernel<<<gemm_blocks, 256, lds, stream>>>(out, W2, bufA, n);
    agg_kernel<<<n, 128, 0, stream>>>(bufA, dinv, row, edges, b2, out, n);
}

// Round 2
// 938.195 us; speedup vs baseline: 1.1946x; 1.1946x over previous
//
#include <hip/hip_runtime.h>
#include <hip/hip_bf16.h>

#define TPB 256
#define SCAN_TILE 1024

// ---------------- preprocessing kernels ----------------

__global__ void count_kernel(const int* __restrict__ dst, int E, int* __restrict__ cnt) {
    int e = blockIdx.x * TPB + threadIdx.x;
    if (e < E) atomicAdd(&cnt[dst[e]], 1);
}

__global__ void dinv_kernel(const int* __restrict__ cnt, float* __restrict__ dinv, int n) {
    int i = blockIdx.x * TPB + threadIdx.x;
    if (i < n) dinv[i] = rsqrtf((float)(cnt[i] + 1));   // +1 self-loop
}

__global__ void scan_reduce(const int* __restrict__ cnt, int* __restrict__ part, int n) {
    __shared__ int sdata[TPB];
    int base = blockIdx.x * SCAN_TILE;
    int t = threadIdx.x;
    int s = 0;
    for (int j = t; j < SCAN_TILE; j += TPB) {
        int i = base + j;
        s += (i < n) ? cnt[i] : 0;
    }
    sdata[t] = s; __syncthreads();
    for (int off = TPB / 2; off > 0; off >>= 1) {
        if (t < off) sdata[t] += sdata[t + off];
        __syncthreads();
    }
    if (t == 0) part[blockIdx.x] = sdata[0];
}

// single block, 512 threads: exclusive scan of part[0..nb), write total to *rowN
__global__ void scan_part(int* __restrict__ part, int nb, int* __restrict__ rowN) {
    __shared__ int sdata[512];
    int t = threadIdx.x;
    int v = (t < nb) ? part[t] : 0;
    sdata[t] = v; __syncthreads();
    for (int off = 1; off < 512; off <<= 1) {
        int xv = (t >= off) ? sdata[t - off] : 0;
        __syncthreads();
        sdata[t] += xv;
        __syncthreads();
    }
    if (t < nb) part[t] = sdata[t] - v;      // exclusive
    if (t == 511) *rowN = sdata[511];        // total = E
}

__global__ void scan_write(const int* __restrict__ cnt, const int* __restrict__ part,
                           int* __restrict__ row, int n) {
    __shared__ int sdata[TPB];
    int t = threadIdx.x;
    int base = blockIdx.x * SCAN_TILE;
    int idx0 = base + t * 4;
    int v[4]; int local = 0;
#pragma unroll
    for (int j = 0; j < 4; j++) {
        int i = idx0 + j;
        v[j] = (i < n) ? cnt[i] : 0;
        local += v[j];
    }
    sdata[t] = local; __syncthreads();
    for (int off = 1; off < TPB; off <<= 1) {
        int xv = (t >= off) ? sdata[t - off] : 0;
        __syncthreads();
        sdata[t] += xv;
        __syncthreads();
    }
    int excl = sdata[t] - local + part[blockIdx.x];
#pragma unroll
    for (int j = 0; j < 4; j++) {
        int i = idx0 + j;
        if (i < n) { row[i] = excl; excl += v[j]; }
    }
}

__global__ void scatter_kernel(const int* __restrict__ src, const int* __restrict__ dst, int E,
                               const float* __restrict__ dinv, const int* __restrict__ row,
                               int* __restrict__ cursor, int2* __restrict__ edges) {
    int e = blockIdx.x * TPB + threadIdx.x;
    if (e >= E) return;
    int s = src[e], d = dst[e];
    int pos = row[d] + atomicAdd(&cursor[d], 1);
    int2 p;
    p.x = s;
    p.y = __float_as_int(dinv[s]);
    edges[pos] = p;
}

// ---------------- GEMM: Hout[n,128] = X[n,128] @ W[128,128] ----------------
// 64 rows per block, 256 threads, each thread computes 4 rows x 8 cols.
// Dynamic LDS: xT[128][64] (32KB) + W[128][128] (64KB) = 96KB.

#define TM 64

__global__ __launch_bounds__(256) void gemm_kernel(const float* __restrict__ X,
                                                   const float* __restrict__ W,
                                                   float* __restrict__ Hout, int n) {
    extern __shared__ float smem[];
    float* xT = smem;                // [k][r] : k*64 + r
    float* Wl = smem + 128 * TM;     // [k][c] : k*128 + c

    int t = threadIdx.x;
    int row0 = blockIdx.x * TM;

    // stage W (16384 floats)
    {
        const float4* Wv = (const float4*)W;
        float4* Wlv = (float4*)Wl;
        for (int j = t; j < 16384 / 4; j += 256) Wlv[j] = Wv[j];
    }
    // stage X transposed
    {
        for (int j = t; j < TM * 32; j += 256) {
            int r = j >> 5;      // row within tile
            int kq = j & 31;     // float4 index along k
            int grow = row0 + r;
            float4 v = (grow < n) ? ((const float4*)X)[(size_t)grow * 32 + kq]
                                  : make_float4(0.f, 0.f, 0.f, 0.f);
            xT[(kq * 4 + 0) * TM + r] = v.x;
            xT[(kq * 4 + 1) * TM + r] = v.y;
            xT[(kq * 4 + 2) * TM + r] = v.z;
            xT[(kq * 4 + 3) * TM + r] = v.w;
        }
    }
    __syncthreads();

    int tx = t & 15;   // col group: cols tx*8..tx*8+7
    int ty = t >> 4;   // row group: rows ty*4..ty*4+3

    float acc[4][8];
#pragma unroll
    for (int r = 0; r < 4; r++)
#pragma unroll
        for (int c = 0; c < 8; c++) acc[r][c] = 0.f;

#pragma unroll 4
    for (int k = 0; k < 128; k++) {
        float4 a  = *(const float4*)&xT[k * TM + ty * 4];
        float4 w0 = *(const float4*)&Wl[k * 128 + tx * 8];
        float4 w1 = *(const float4*)&Wl[k * 128 + tx * 8 + 4];
        float av[4] = {a.x, a.y, a.z, a.w};
        float wv[8] = {w0.x, w0.y, w0.z, w0.w, w1.x, w1.y, w1.z, w1.w};
#pragma unroll
        for (int r = 0; r < 4; r++)
#pragma unroll
            for (int c = 0; c < 8; c++) acc[r][c] += av[r] * wv[c];
    }

#pragma unroll
    for (int r = 0; r < 4; r++) {
        int grow = row0 + ty * 4 + r;
        if (grow < n) {
            float4* o = (float4*)&Hout[(size_t)grow * 128 + tx * 8];
            o[0] = make_float4(acc[r][0], acc[r][1], acc[r][2], acc[r][3]);
            o[1] = make_float4(acc[r][4], acc[r][5], acc[r][6], acc[r][7]);
        }
    }
}

// ---------------- aggregation v2 ----------------
// out[i] = relu( sum_{e in N(i)} w_e*di * h[src_e] + di^2 * h[i] + b )
// 256 threads/block = 8 nodes/block; 32 lanes per node, float4 (16B) per lane.
// Edge walk unrolled x4: 4 independent 512B row-gathers in flight per group.

__global__ __launch_bounds__(256) void agg_kernel(const float* __restrict__ h,
                                                  const float* __restrict__ dinv,
                                                  const int* __restrict__ row,
                                                  const int2* __restrict__ edges,
                                                  const float* __restrict__ bias,
                                                  float* __restrict__ out, int n) {
    int g    = threadIdx.x >> 5;          // node slot 0..7
    int lane = threadIdx.x & 31;          // float4 index 0..31
    int i = blockIdx.x * 8 + g;
    if (i >= n) return;

    const float4* h4 = (const float4*)h;
    float di = dinv[i];

    float4 self = h4[(size_t)i * 32 + lane];
    float s2 = di * di;
    float ax = self.x * s2, ay = self.y * s2, az = self.z * s2, aw = self.w * s2;

    int e0 = row[i], e1 = row[i + 1];
    int e = e0;

    for (; e + 4 <= e1; e += 4) {
        int2 p0 = edges[e + 0];
        int2 p1 = edges[e + 1];
        int2 p2 = edges[e + 2];
        int2 p3 = edges[e + 3];
        float4 v0 = h4[(size_t)p0.x * 32 + lane];
        float4 v1 = h4[(size_t)p1.x * 32 + lane];
        float4 v2 = h4[(size_t)p2.x * 32 + lane];
        float4 v3 = h4[(size_t)p3.x * 32 + lane];
        float w0 = __int_as_float(p0.y) * di;
        float w1 = __int_as_float(p1.y) * di;
        float w2 = __int_as_float(p2.y) * di;
        float w3 = __int_as_float(p3.y) * di;
        ax += w0 * v0.x + w1 * v1.x + w2 * v2.x + w3 * v3.x;
        ay += w0 * v0.y + w1 * v1.y + w2 * v2.y + w3 * v3.y;
        az += w0 * v0.z + w1 * v1.z + w2 * v2.z + w3 * v3.z;
        aw += w0 * v0.w + w1 * v1.w + w2 * v2.w + w3 * v3.w;
    }
    for (; e < e1; ++e) {
        int2 p = edges[e];
        float4 v = h4[(size_t)p.x * 32 + lane];
        float w = __int_as_float(p.y) * di;
        ax += w * v.x; ay += w * v.y; az += w * v.z; aw += w * v.w;
    }

    const float4* b4 = (const float4*)bias;
    float4 b = b4[lane];
    float4 o;
    o.x = fmaxf(ax + b.x, 0.f);
    o.y = fmaxf(ay + b.y, 0.f);
    o.z = fmaxf(az + b.z, 0.f);
    o.w = fmaxf(aw + b.w, 0.f);
    ((float4*)out)[(size_t)i * 32 + lane] = o;
}

// ---------------- launch ----------------

extern "C" void kernel_launch(void* const* d_in, const int* in_sizes, int n_in,
                              void* d_out, int out_size, void* d_ws, size_t ws_size,
                              hipStream_t stream) {
    const float* x  = (const float*)d_in[0];
    const int*   ei = (const int*)d_in[1];
    const float* W0 = (const float*)d_in[2];
    const float* b0 = (const float*)d_in[3];
    const float* W1 = (const float*)d_in[4];
    const float* b1 = (const float*)d_in[5];
    const float* W2 = (const float*)d_in[6];
    const float* b2 = (const float*)d_in[7];

    const int H = 128;
    int n = in_sizes[0] / H;
    int E = in_sizes[1] / 2;
    const int* srcp = ei;
    const int* dstp = ei + E;

    // workspace bump allocator
    char* p = (char*)d_ws;
    auto alloc = [&](size_t bytes) {
        void* r = (void*)p;
        p += (bytes + 255) & ~(size_t)255;
        return r;
    };
    float* bufA  = (float*)alloc((size_t)n * H * sizeof(float));   // 51.2 MB
    int*  cnt    = (int*)alloc((size_t)n * sizeof(int));
    int*  cursor = (int*)alloc((size_t)n * sizeof(int));
    float* dinv  = (float*)alloc((size_t)n * sizeof(float));
    int*  row    = (int*)alloc((size_t)(n + 1) * sizeof(int));
    int*  part   = (int*)alloc(512 * sizeof(int));
    int2* edges  = (int2*)alloc((size_t)E * sizeof(int2));         // 12.8 MB

    hipMemsetAsync(cnt, 0, (size_t)n * sizeof(int), stream);
    hipMemsetAsync(cursor, 0, (size_t)n * sizeof(int), stream);

    count_kernel<<<(E + TPB - 1) / TPB, TPB, 0, stream>>>(dstp, E, cnt);
    dinv_kernel<<<(n + TPB - 1) / TPB, TPB, 0, stream>>>(cnt, dinv, n);

    int nb = (n + SCAN_TILE - 1) / SCAN_TILE;
    scan_reduce<<<nb, TPB, 0, stream>>>(cnt, part, n);
    scan_part<<<1, 512, 0, stream>>>(part, nb, &row[n]);
    scan_write<<<nb, TPB, 0, stream>>>(cnt, part, row, n);
    scatter_kernel<<<(E + TPB - 1) / TPB, TPB, 0, stream>>>(srcp, dstp, E, dinv, row, cursor, edges);

    float* out = (float*)d_out;
    size_t lds = (size_t)(128 * TM + 128 * 128) * sizeof(float);   // 96 KB
    int gemm_blocks = (n + TM - 1) / TM;
    int agg_blocks = (n + 7) / 8;

    // layer 0: x -> bufA -> out
    gemm_kernel<<<gemm_blocks, 256, lds, stream>>>(x, W0, bufA, n);
    agg_kernel<<<agg_blocks, 256, 0, stream>>>(bufA, dinv, row, edges, b0, out, n);
    // layer 1: out -> bufA -> out
    gemm_kernel<<<gemm_blocks, 256, lds, stream>>>(out, W1, bufA, n);
    agg_kernel<<<agg_blocks, 256, 0, stream>>>(bufA, dinv, row, edges, b1, out, n);
    // layer 2: out -> bufA -> out
    gemm_kernel<<<gemm_blocks, 256, lds, stream>>>(out, W2, bufA, n);
    agg_kernel<<<agg_blocks, 256, 0, stream>>>(bufA, dinv, row, edges, b2, out, n);
}

// Round 3
// 746.058 us; speedup vs baseline: 1.5023x; 1.2575x over previous
//
#include <hip/hip_runtime.h>
#include <hip/hip_bf16.h>

#define TPB 256
#define SCAN_TILE 1024

typedef short s8v __attribute__((ext_vector_type(8)));   // 8 bf16 in 4 VGPRs
typedef float f4v __attribute__((ext_vector_type(4)));

// ---- fp32 -> bf16 split helpers (RNE) ----
__device__ __forceinline__ unsigned short bf16_rne(float v) {
    unsigned int u = __float_as_uint(v);
    u += 0x7fffu + ((u >> 16) & 1u);
    return (unsigned short)(u >> 16);
}
__device__ __forceinline__ void split_bf16(float v, unsigned short& hi, unsigned short& lo) {
    hi = bf16_rne(v);
    float hf = __uint_as_float((unsigned int)hi << 16);
    lo = bf16_rne(v - hf);
}

// ---------------- preprocessing kernels ----------------

__global__ void count_kernel(const int* __restrict__ dst, int E, int* __restrict__ cnt) {
    int e = blockIdx.x * TPB + threadIdx.x;
    if (e < E) atomicAdd(&cnt[dst[e]], 1);
}

__global__ void dinv_kernel(const int* __restrict__ cnt, float* __restrict__ dinv, int n) {
    int i = blockIdx.x * TPB + threadIdx.x;
    if (i < n) dinv[i] = rsqrtf((float)(cnt[i] + 1));   // +1 self-loop
}

__global__ void scan_reduce(const int* __restrict__ cnt, int* __restrict__ part, int n) {
    __shared__ int sdata[TPB];
    int base = blockIdx.x * SCAN_TILE;
    int t = threadIdx.x;
    int s = 0;
    for (int j = t; j < SCAN_TILE; j += TPB) {
        int i = base + j;
        s += (i < n) ? cnt[i] : 0;
    }
    sdata[t] = s; __syncthreads();
    for (int off = TPB / 2; off > 0; off >>= 1) {
        if (t < off) sdata[t] += sdata[t + off];
        __syncthreads();
    }
    if (t == 0) part[blockIdx.x] = sdata[0];
}

__global__ void scan_part(int* __restrict__ part, int nb, int* __restrict__ rowN) {
    __shared__ int sdata[512];
    int t = threadIdx.x;
    int v = (t < nb) ? part[t] : 0;
    sdata[t] = v; __syncthreads();
    for (int off = 1; off < 512; off <<= 1) {
        int xv = (t >= off) ? sdata[t - off] : 0;
        __syncthreads();
        sdata[t] += xv;
        __syncthreads();
    }
    if (t < nb) part[t] = sdata[t] - v;      // exclusive
    if (t == 511) *rowN = sdata[511];        // total = E
}

__global__ void scan_write(const int* __restrict__ cnt, const int* __restrict__ part,
                           int* __restrict__ row, int n) {
    __shared__ int sdata[TPB];
    int t = threadIdx.x;
    int base = blockIdx.x * SCAN_TILE;
    int idx0 = base + t * 4;
    int v[4]; int local = 0;
#pragma unroll
    for (int j = 0; j < 4; j++) {
        int i = idx0 + j;
        v[j] = (i < n) ? cnt[i] : 0;
        local += v[j];
    }
    sdata[t] = local; __syncthreads();
    for (int off = 1; off < TPB; off <<= 1) {
        int xv = (t >= off) ? sdata[t - off] : 0;
        __syncthreads();
        sdata[t] += xv;
        __syncthreads();
    }
    int excl = sdata[t] - local + part[blockIdx.x];
#pragma unroll
    for (int j = 0; j < 4; j++) {
        int i = idx0 + j;
        if (i < n) { row[i] = excl; excl += v[j]; }
    }
}

__global__ void scatter_kernel(const int* __restrict__ src, const int* __restrict__ dst, int E,
                               const float* __restrict__ dinv, const int* __restrict__ row,
                               int* __restrict__ cursor, int2* __restrict__ edges) {
    int e = blockIdx.x * TPB + threadIdx.x;
    if (e >= E) return;
    int s = src[e], d = dst[e];
    int pos = row[d] + atomicAdd(&cursor[d], 1);
    int2 p;
    p.x = s;
    p.y = __float_as_int(dinv[s]);
    edges[pos] = p;
}

// Split + swizzle W into B-fragment order for mfma_f32_16x16x32_bf16.
// B-frag layout: lane holds B[k=(lane>>4)*8+j][ncol=lane&15], j=0..7 contiguous.
// Fragment index for (col_tile ct 0..7, k_iter kki 0..3): ((ct*4+kki)*64+lane)*8+j
__global__ void wsplit_kernel(const float* __restrict__ W0, const float* __restrict__ W1,
                              const float* __restrict__ W2,
                              unsigned short* __restrict__ Whi, unsigned short* __restrict__ Wlo) {
    int t = blockIdx.x * TPB + threadIdx.x;           // 0 .. 3*16384
    if (t >= 3 * 16384) return;
    int layer = t >> 14;
    int e = t & 16383;
    int k = e >> 7, ncol = e & 127;
    const float* W = (layer == 0) ? W0 : (layer == 1) ? W1 : W2;
    unsigned short hi, lo;
    split_bf16(W[e], hi, lo);
    int ct = ncol >> 4;
    int lane = (((k >> 3) & 3) << 4) | (ncol & 15);
    int kki = k >> 5;
    int j = k & 7;
    int idx = layer * 16384 + (((ct * 4 + kki) * 64 + lane) * 8 + j);
    Whi[idx] = hi; Wlo[idx] = lo;
}

// split x (fp32, row-major n x 128) into hi/lo bf16 arrays (same layout)
__global__ void xsplit_kernel(const float* __restrict__ x,
                              unsigned short* __restrict__ xhi, unsigned short* __restrict__ xlo,
                              long total4) {
    long t = (long)blockIdx.x * TPB + threadIdx.x;
    if (t >= total4) return;
    float4 v = ((const float4*)x)[t];
    ushort4 h, l;
    split_bf16(v.x, h.x, l.x); split_bf16(v.y, h.y, l.y);
    split_bf16(v.z, h.z, l.z); split_bf16(v.w, h.w, l.w);
    ((ushort4*)xhi)[t] = h;
    ((ushort4*)xlo)[t] = l;
}

// ---------------- GEMM via split-bf16 MFMA ----------------
// C[n,128] = A[n,128] @ W[128,128], A given as hi/lo bf16, C fp32.
// Block: 256 thr = 4 waves; block tile 128 rows x 128 cols.
// wave: ch = wave&1 (col half, 64 cols = 4 col-tiles), rh = wave>>1 (row half, 64 rows = 4 row-tiles).
// B-frags (hi+lo, 4 ct x 4 kki) loaded once into 128 VGPRs; A-frags streamed from global;
// no LDS, no bank conflicts. 3 mfma per (rt,ct,kki): hi*hi + hi*lo + lo*hi.

__global__ __launch_bounds__(256, 2) void gemm_mfma(const unsigned short* __restrict__ Ahg,
                                                    const unsigned short* __restrict__ Alg,
                                                    const unsigned short* __restrict__ Whs,
                                                    const unsigned short* __restrict__ Wls,
                                                    float* __restrict__ C, int n) {
    int t = threadIdx.x;
    int wave = t >> 6, lane = t & 63;
    int ch = wave & 1, rh = wave >> 1;
    int lm = lane & 15, q = lane >> 4;
    long row0 = (long)blockIdx.x * 128 + rh * 64;

    const s8v* Wh8 = (const s8v*)Whs;
    const s8v* Wl8 = (const s8v*)Wls;
    s8v Bh[4][4], Bl[4][4];
#pragma unroll
    for (int ct = 0; ct < 4; ct++)
#pragma unroll
        for (int kki = 0; kki < 4; kki++) {
            int idx = (((ch * 4 + ct) * 4 + kki) * 64) + lane;
            Bh[ct][kki] = Wh8[idx];
            Bl[ct][kki] = Wl8[idx];
        }

    f4v acc[4][4];
#pragma unroll
    for (int rt = 0; rt < 4; rt++)
#pragma unroll
        for (int ct = 0; ct < 4; ct++) acc[rt][ct] = (f4v)0.0f;

    const s8v* A8h = (const s8v*)Ahg;
    const s8v* A8l = (const s8v*)Alg;

#pragma unroll
    for (int kki = 0; kki < 4; kki++) {
        s8v ah[4], al[4];
#pragma unroll
        for (int rt = 0; rt < 4; rt++) {
            long r = row0 + rt * 16 + lm;
            long base = r * 16 + kki * 4 + q;    // units of 8 shorts (16B)
            ah[rt] = A8h[base];
            al[rt] = A8l[base];
        }
#pragma unroll
        for (int rt = 0; rt < 4; rt++)
#pragma unroll
            for (int ct = 0; ct < 4; ct++) {
                acc[rt][ct] = __builtin_amdgcn_mfma_f32_16x16x32_bf16(ah[rt], Bh[ct][kki], acc[rt][ct], 0, 0, 0);
                acc[rt][ct] = __builtin_amdgcn_mfma_f32_16x16x32_bf16(ah[rt], Bl[ct][kki], acc[rt][ct], 0, 0, 0);
                acc[rt][ct] = __builtin_amdgcn_mfma_f32_16x16x32_bf16(al[rt], Bh[ct][kki], acc[rt][ct], 0, 0, 0);
            }
    }

    // C/D layout: col = lane&15 (+tile base), row = (lane>>4)*4 + reg (+tile base)
#pragma unroll
    for (int rt = 0; rt < 4; rt++) {
        long rbase = row0 + rt * 16 + q * 4;
#pragma unroll
        for (int reg = 0; reg < 4; reg++) {
            long r = rbase + reg;
            if (r < n) {
#pragma unroll
                for (int ct = 0; ct < 4; ct++)
                    C[r * 128 + ch * 64 + ct * 16 + lm] = acc[rt][ct][reg];
            }
        }
    }
}

// ---------------- aggregation ----------------
// out[i] = relu( sum_e w_e*di*h[src_e] + di^2*h[i] + b ); 8 nodes/block, 32 lanes/node, float4/lane.
// SPLIT=true: write hi/lo bf16 (feeds next gemm); SPLIT=false: write fp32 d_out.

template <bool SPLIT>
__global__ __launch_bounds__(256) void agg_kernel(const float* __restrict__ h,
                                                  const float* __restrict__ dinv,
                                                  const int* __restrict__ row,
                                                  const int2* __restrict__ edges,
                                                  const float* __restrict__ bias,
                                                  float* __restrict__ out,
                                                  unsigned short* __restrict__ ohi,
                                                  unsigned short* __restrict__ olo, int n) {
    int g    = threadIdx.x >> 5;
    int lane = threadIdx.x & 31;
    int i = blockIdx.x * 8 + g;
    if (i >= n) return;

    const float4* h4 = (const float4*)h;
    float di = dinv[i];

    float4 self = h4[(size_t)i * 32 + lane];
    float s2 = di * di;
    float ax = self.x * s2, ay = self.y * s2, az = self.z * s2, aw = self.w * s2;

    int e0 = row[i], e1 = row[i + 1];
    int e = e0;

    for (; e + 4 <= e1; e += 4) {
        int2 p0 = edges[e + 0];
        int2 p1 = edges[e + 1];
        int2 p2 = edges[e + 2];
        int2 p3 = edges[e + 3];
        float4 v0 = h4[(size_t)p0.x * 32 + lane];
        float4 v1 = h4[(size_t)p1.x * 32 + lane];
        float4 v2 = h4[(size_t)p2.x * 32 + lane];
        float4 v3 = h4[(size_t)p3.x * 32 + lane];
        float w0 = __int_as_float(p0.y) * di;
        float w1 = __int_as_float(p1.y) * di;
        float w2 = __int_as_float(p2.y) * di;
        float w3 = __int_as_float(p3.y) * di;
        ax += w0 * v0.x + w1 * v1.x + w2 * v2.x + w3 * v3.x;
        ay += w0 * v0.y + w1 * v1.y + w2 * v2.y + w3 * v3.y;
        az += w0 * v0.z + w1 * v1.z + w2 * v2.z + w3 * v3.z;
        aw += w0 * v0.w + w1 * v1.w + w2 * v2.w + w3 * v3.w;
    }
    for (; e < e1; ++e) {
        int2 p = edges[e];
        float4 v = h4[(size_t)p.x * 32 + lane];
        float w = __int_as_float(p.y) * di;
        ax += w * v.x; ay += w * v.y; az += w * v.z; aw += w * v.w;
    }

    const float4* b4 = (const float4*)bias;
    float4 b = b4[lane];
    float ox = fmaxf(ax + b.x, 0.f);
    float oy = fmaxf(ay + b.y, 0.f);
    float oz = fmaxf(az + b.z, 0.f);
    float ow = fmaxf(aw + b.w, 0.f);

    if (SPLIT) {
        ushort4 hq, lq;
        split_bf16(ox, hq.x, lq.x); split_bf16(oy, hq.y, lq.y);
        split_bf16(oz, hq.z, lq.z); split_bf16(ow, hq.w, lq.w);
        ((ushort4*)ohi)[(size_t)i * 32 + lane] = hq;
        ((ushort4*)olo)[(size_t)i * 32 + lane] = lq;
    } else {
        float4 o = make_float4(ox, oy, oz, ow);
        ((float4*)out)[(size_t)i * 32 + lane] = o;
    }
}

// ---------------- launch ----------------

extern "C" void kernel_launch(void* const* d_in, const int* in_sizes, int n_in,
                              void* d_out, int out_size, void* d_ws, size_t ws_size,
                              hipStream_t stream) {
    const float* x  = (const float*)d_in[0];
    const int*   ei = (const int*)d_in[1];
    const float* W0 = (const float*)d_in[2];
    const float* b0 = (const float*)d_in[3];
    const float* W1 = (const float*)d_in[4];
    const float* b1 = (const float*)d_in[5];
    const float* W2 = (const float*)d_in[6];
    const float* b2 = (const float*)d_in[7];

    const int H = 128;
    int n = in_sizes[0] / H;
    int E = in_sizes[1] / 2;
    const int* srcp = ei;
    const int* dstp = ei + E;

    int gemm_blocks = (n + 127) / 128;
    long npad = (long)gemm_blocks * 128;

    // workspace bump allocator
    char* p = (char*)d_ws;
    auto alloc = [&](size_t bytes) {
        void* r = (void*)p;
        p += (bytes + 255) & ~(size_t)255;
        return r;
    };
    float* bufA = (float*)alloc((size_t)npad * H * sizeof(float));          // 51.25 MB
    unsigned short* sh = (unsigned short*)alloc((size_t)npad * H * 2);      // 25.6 MB
    unsigned short* sl = (unsigned short*)alloc((size_t)npad * H * 2);      // 25.6 MB
    unsigned short* Whs = (unsigned short*)alloc(3 * 16384 * 2);
    unsigned short* Wls = (unsigned short*)alloc(3 * 16384 * 2);
    int*  cnt    = (int*)alloc((size_t)n * sizeof(int));
    int*  cursor = (int*)alloc((size_t)n * sizeof(int));
    float* dinv  = (float*)alloc((size_t)n * sizeof(float));
    int*  row    = (int*)alloc((size_t)(n + 1) * sizeof(int));
    int*  part   = (int*)alloc(512 * sizeof(int));
    int2* edges  = (int2*)alloc((size_t)E * sizeof(int2));                  // 12.8 MB

    hipMemsetAsync(cnt, 0, (size_t)n * sizeof(int), stream);
    hipMemsetAsync(cursor, 0, (size_t)n * sizeof(int), stream);

    count_kernel<<<(E + TPB - 1) / TPB, TPB, 0, stream>>>(dstp, E, cnt);
    dinv_kernel<<<(n + TPB - 1) / TPB, TPB, 0, stream>>>(cnt, dinv, n);

    int nb = (n + SCAN_TILE - 1) / SCAN_TILE;
    scan_reduce<<<nb, TPB, 0, stream>>>(cnt, part, n);
    scan_part<<<1, 512, 0, stream>>>(part, nb, &row[n]);
    scan_write<<<nb, TPB, 0, stream>>>(cnt, part, row, n);
    scatter_kernel<<<(E + TPB - 1) / TPB, TPB, 0, stream>>>(srcp, dstp, E, dinv, row, cursor, edges);

    wsplit_kernel<<<(3 * 16384 + TPB - 1) / TPB, TPB, 0, stream>>>(W0, W1, W2, Whs, Wls);
    long total4 = (long)n * 32;
    xsplit_kernel<<<(int)((total4 + TPB - 1) / TPB), TPB, 0, stream>>>(x, sh, sl, total4);

    float* out = (float*)d_out;
    int agg_blocks = (n + 7) / 8;

    // layer 0
    gemm_mfma<<<gemm_blocks, 256, 0, stream>>>(sh, sl, Whs, Wls, bufA, n);
    agg_kernel<true><<<agg_blocks, 256, 0, stream>>>(bufA, dinv, row, edges, b0, nullptr, sh, sl, n);
    // layer 1
    gemm_mfma<<<gemm_blocks, 256, 0, stream>>>(sh, sl, Whs + 16384, Wls + 16384, bufA, n);
    agg_kernel<true><<<agg_blocks, 256, 0, stream>>>(bufA, dinv, row, edges, b1, nullptr, sh, sl, n);
    // layer 2
    gemm_mfma<<<gemm_blocks, 256, 0, stream>>>(sh, sl, Whs + 32768, Wls + 32768, bufA, n);
    agg_kernel<false><<<agg_blocks, 256, 0, stream>>>(bufA, dinv, row, edges, b2, out, nullptr, nullptr, n);
}

// Round 4
// 593.008 us; speedup vs baseline: 1.8900x; 1.2581x over previous
//
#include <hip/hip_runtime.h>
#include <hip/hip_bf16.h>

#define TPB 256
#define SCAN_TILE 1024

typedef short s8v __attribute__((ext_vector_type(8)));     // 8 bf16 in 4 VGPRs
typedef float f4v __attribute__((ext_vector_type(4)));
typedef _Float16 h8v __attribute__((ext_vector_type(8)));  // 8 fp16 in 4 VGPRs

// ---- fp32 -> bf16 split helpers (RNE) ----
__device__ __forceinline__ unsigned short bf16_rne(float v) {
    unsigned int u = __float_as_uint(v);
    u += 0x7fffu + ((u >> 16) & 1u);
    return (unsigned short)(u >> 16);
}
__device__ __forceinline__ void split_bf16(float v, unsigned short& hi, unsigned short& lo) {
    hi = bf16_rne(v);
    float hf = __uint_as_float((unsigned int)hi << 16);
    lo = bf16_rne(v - hf);
}

// ---------------- preprocessing kernels ----------------

__global__ void count_kernel(const int* __restrict__ dst, int E, int* __restrict__ cnt) {
    int e = blockIdx.x * TPB + threadIdx.x;
    if (e < E) atomicAdd(&cnt[dst[e]], 1);
}

__global__ void dinv_kernel(const int* __restrict__ cnt, float* __restrict__ dinv, int n) {
    int i = blockIdx.x * TPB + threadIdx.x;
    if (i < n) dinv[i] = rsqrtf((float)(cnt[i] + 1));   // +1 self-loop
}

__global__ void scan_reduce(const int* __restrict__ cnt, int* __restrict__ part, int n) {
    __shared__ int sdata[TPB];
    int base = blockIdx.x * SCAN_TILE;
    int t = threadIdx.x;
    int s = 0;
    for (int j = t; j < SCAN_TILE; j += TPB) {
        int i = base + j;
        s += (i < n) ? cnt[i] : 0;
    }
    sdata[t] = s; __syncthreads();
    for (int off = TPB / 2; off > 0; off >>= 1) {
        if (t < off) sdata[t] += sdata[t + off];
        __syncthreads();
    }
    if (t == 0) part[blockIdx.x] = sdata[0];
}

__global__ void scan_part(int* __restrict__ part, int nb, int* __restrict__ rowN) {
    __shared__ int sdata[512];
    int t = threadIdx.x;
    int v = (t < nb) ? part[t] : 0;
    sdata[t] = v; __syncthreads();
    for (int off = 1; off < 512; off <<= 1) {
        int xv = (t >= off) ? sdata[t - off] : 0;
        __syncthreads();
        sdata[t] += xv;
        __syncthreads();
    }
    if (t < nb) part[t] = sdata[t] - v;      // exclusive
    if (t == 511) *rowN = sdata[511];        // total = E
}

__global__ void scan_write(const int* __restrict__ cnt, const int* __restrict__ part,
                           int* __restrict__ row, int n) {
    __shared__ int sdata[TPB];
    int t = threadIdx.x;
    int base = blockIdx.x * SCAN_TILE;
    int idx0 = base + t * 4;
    int v[4]; int local = 0;
#pragma unroll
    for (int j = 0; j < 4; j++) {
        int i = idx0 + j;
        v[j] = (i < n) ? cnt[i] : 0;
        local += v[j];
    }
    sdata[t] = local; __syncthreads();
    for (int off = 1; off < TPB; off <<= 1) {
        int xv = (t >= off) ? sdata[t - off] : 0;
        __syncthreads();
        sdata[t] += xv;
        __syncthreads();
    }
    int excl = sdata[t] - local + part[blockIdx.x];
#pragma unroll
    for (int j = 0; j < 4; j++) {
        int i = idx0 + j;
        if (i < n) { row[i] = excl; excl += v[j]; }
    }
}

// edges: src index only (weight recovered via dinv[src] lookup in agg)
__global__ void scatter_kernel(const int* __restrict__ src, const int* __restrict__ dst, int E,
                               const int* __restrict__ row,
                               int* __restrict__ cursor, int* __restrict__ esrc) {
    int e = blockIdx.x * TPB + threadIdx.x;
    if (e >= E) return;
    int s = src[e], d = dst[e];
    int pos = row[d] + atomicAdd(&cursor[d], 1);
    esrc[pos] = s;
}

// Split + swizzle W into B-fragment order for mfma_f32_16x16x32_bf16.
__global__ void wsplit_kernel(const float* __restrict__ W0, const float* __restrict__ W1,
                              const float* __restrict__ W2,
                              unsigned short* __restrict__ Whi, unsigned short* __restrict__ Wlo) {
    int t = blockIdx.x * TPB + threadIdx.x;           // 0 .. 3*16384
    if (t >= 3 * 16384) return;
    int layer = t >> 14;
    int e = t & 16383;
    int k = e >> 7, ncol = e & 127;
    const float* W = (layer == 0) ? W0 : (layer == 1) ? W1 : W2;
    unsigned short hi, lo;
    split_bf16(W[e], hi, lo);
    int ct = ncol >> 4;
    int lane = (((k >> 3) & 3) << 4) | (ncol & 15);
    int kki = k >> 5;
    int j = k & 7;
    int idx = layer * 16384 + (((ct * 4 + kki) * 64 + lane) * 8 + j);
    Whi[idx] = hi; Wlo[idx] = lo;
}

// split x (fp32, row-major n x 128) into hi/lo bf16 arrays (same layout)
__global__ void xsplit_kernel(const float* __restrict__ x,
                              unsigned short* __restrict__ xhi, unsigned short* __restrict__ xlo,
                              long total4) {
    long t = (long)blockIdx.x * TPB + threadIdx.x;
    if (t >= total4) return;
    float4 v = ((const float4*)x)[t];
    ushort4 h, l;
    split_bf16(v.x, h.x, l.x); split_bf16(v.y, h.y, l.y);
    split_bf16(v.z, h.z, l.z); split_bf16(v.w, h.w, l.w);
    ((ushort4*)xhi)[t] = h;
    ((ushort4*)xlo)[t] = l;
}

// ---------------- GEMM via split-bf16 MFMA ----------------
// C[n,128] = A[n,128] @ W[128,128]; writes fp32 C (for agg self term) + fp16 Ch (gather copy).

__global__ __launch_bounds__(256, 2) void gemm_mfma(const unsigned short* __restrict__ Ahg,
                                                    const unsigned short* __restrict__ Alg,
                                                    const unsigned short* __restrict__ Whs,
                                                    const unsigned short* __restrict__ Wls,
                                                    float* __restrict__ C,
                                                    _Float16* __restrict__ Ch, int n) {
    int t = threadIdx.x;
    int wave = t >> 6, lane = t & 63;
    int ch = wave & 1, rh = wave >> 1;
    int lm = lane & 15, q = lane >> 4;
    long row0 = (long)blockIdx.x * 128 + rh * 64;

    const s8v* Wh8 = (const s8v*)Whs;
    const s8v* Wl8 = (const s8v*)Wls;
    s8v Bh[4][4], Bl[4][4];
#pragma unroll
    for (int ct = 0; ct < 4; ct++)
#pragma unroll
        for (int kki = 0; kki < 4; kki++) {
            int idx = (((ch * 4 + ct) * 4 + kki) * 64) + lane;
            Bh[ct][kki] = Wh8[idx];
            Bl[ct][kki] = Wl8[idx];
        }

    f4v acc[4][4];
#pragma unroll
    for (int rt = 0; rt < 4; rt++)
#pragma unroll
        for (int ct = 0; ct < 4; ct++) acc[rt][ct] = (f4v)0.0f;

    const s8v* A8h = (const s8v*)Ahg;
    const s8v* A8l = (const s8v*)Alg;

#pragma unroll
    for (int kki = 0; kki < 4; kki++) {
        s8v ah[4], al[4];
#pragma unroll
        for (int rt = 0; rt < 4; rt++) {
            long r = row0 + rt * 16 + lm;
            long base = r * 16 + kki * 4 + q;    // units of 8 shorts (16B)
            ah[rt] = A8h[base];
            al[rt] = A8l[base];
        }
#pragma unroll
        for (int rt = 0; rt < 4; rt++)
#pragma unroll
            for (int ct = 0; ct < 4; ct++) {
                acc[rt][ct] = __builtin_amdgcn_mfma_f32_16x16x32_bf16(ah[rt], Bh[ct][kki], acc[rt][ct], 0, 0, 0);
                acc[rt][ct] = __builtin_amdgcn_mfma_f32_16x16x32_bf16(ah[rt], Bl[ct][kki], acc[rt][ct], 0, 0, 0);
                acc[rt][ct] = __builtin_amdgcn_mfma_f32_16x16x32_bf16(al[rt], Bh[ct][kki], acc[rt][ct], 0, 0, 0);
            }
    }

    // C/D layout: col = lane&15 (+tile base), row = (lane>>4)*4 + reg (+tile base)
#pragma unroll
    for (int rt = 0; rt < 4; rt++) {
        long rbase = row0 + rt * 16 + q * 4;
#pragma unroll
        for (int reg = 0; reg < 4; reg++) {
            long r = rbase + reg;
            if (r < n) {
#pragma unroll
                for (int ct = 0; ct < 4; ct++) {
                    float v = acc[rt][ct][reg];
                    long col = ch * 64 + ct * 16 + lm;
                    C[r * 128 + col] = v;
                    Ch[r * 128 + col] = (_Float16)v;
                }
            }
        }
    }
}

// ---------------- aggregation v3 ----------------
// out[i] = relu( sum_e dinv[s]*di*h[s] + di^2*h[i] + b )
// 256 thr = 16 nodes/block; 16 lanes/node, 8 features (16B fp16) per lane.
// Gather from fp16 copy (half traffic); self term from fp32 (exact pass-through).

template <bool SPLIT>
__global__ __launch_bounds__(256) void agg_kernel(const float* __restrict__ hA,
                                                  const h8v* __restrict__ hH,
                                                  const float* __restrict__ dinv,
                                                  const int* __restrict__ row,
                                                  const int* __restrict__ esrc,
                                                  const float* __restrict__ bias,
                                                  float* __restrict__ out,
                                                  unsigned short* __restrict__ ohi,
                                                  unsigned short* __restrict__ olo, int n) {
    int g    = threadIdx.x >> 4;          // node slot 0..15
    int lane = threadIdx.x & 15;          // feature block (8 feats)
    int i = blockIdx.x * 16 + g;
    if (i >= n) return;

    float di = dinv[i];
    float s2 = di * di;

    const float4* a4 = (const float4*)(hA + (size_t)i * 128 + lane * 8);
    float4 sA = a4[0], sB = a4[1];
    float acc[8];
    acc[0] = sA.x * s2; acc[1] = sA.y * s2; acc[2] = sA.z * s2; acc[3] = sA.w * s2;
    acc[4] = sB.x * s2; acc[5] = sB.y * s2; acc[6] = sB.z * s2; acc[7] = sB.w * s2;

    int e0 = row[i], e1 = row[i + 1];
    int e = e0;

    for (; e + 4 <= e1; e += 4) {
        int s0 = esrc[e + 0];
        int s1 = esrc[e + 1];
        int s2i = esrc[e + 2];
        int s3 = esrc[e + 3];
        h8v v0 = hH[(size_t)s0 * 16 + lane];
        h8v v1 = hH[(size_t)s1 * 16 + lane];
        h8v v2 = hH[(size_t)s2i * 16 + lane];
        h8v v3 = hH[(size_t)s3 * 16 + lane];
        float w0 = dinv[s0] * di;
        float w1 = dinv[s1] * di;
        float w2 = dinv[s2i] * di;
        float w3 = dinv[s3] * di;
#pragma unroll
        for (int k = 0; k < 8; k++)
            acc[k] += w0 * (float)v0[k] + w1 * (float)v1[k] + w2 * (float)v2[k] + w3 * (float)v3[k];
    }
    for (; e < e1; ++e) {
        int s = esrc[e];
        h8v v = hH[(size_t)s * 16 + lane];
        float w = dinv[s] * di;
#pragma unroll
        for (int k = 0; k < 8; k++) acc[k] += w * (float)v[k];
    }

    const float4* b4 = (const float4*)(bias + lane * 8);
    float4 bA = b4[0], bB = b4[1];
    float o[8];
    o[0] = fmaxf(acc[0] + bA.x, 0.f); o[1] = fmaxf(acc[1] + bA.y, 0.f);
    o[2] = fmaxf(acc[2] + bA.z, 0.f); o[3] = fmaxf(acc[3] + bA.w, 0.f);
    o[4] = fmaxf(acc[4] + bB.x, 0.f); o[5] = fmaxf(acc[5] + bB.y, 0.f);
    o[6] = fmaxf(acc[6] + bB.z, 0.f); o[7] = fmaxf(acc[7] + bB.w, 0.f);

    if (SPLIT) {
        ushort4 h0, l0, h1, l1;
        split_bf16(o[0], h0.x, l0.x); split_bf16(o[1], h0.y, l0.y);
        split_bf16(o[2], h0.z, l0.z); split_bf16(o[3], h0.w, l0.w);
        split_bf16(o[4], h1.x, l1.x); split_bf16(o[5], h1.y, l1.y);
        split_bf16(o[6], h1.z, l1.z); split_bf16(o[7], h1.w, l1.w);
        ushort4* oh = (ushort4*)(ohi + (size_t)i * 128 + lane * 8);
        ushort4* ol = (ushort4*)(olo + (size_t)i * 128 + lane * 8);
        oh[0] = h0; oh[1] = h1;
        ol[0] = l0; ol[1] = l1;
    } else {
        float4* o4 = (float4*)(out + (size_t)i * 128 + lane * 8);
        o4[0] = make_float4(o[0], o[1], o[2], o[3]);
        o4[1] = make_float4(o[4], o[5], o[6], o[7]);
    }
}

// ---------------- launch ----------------

extern "C" void kernel_launch(void* const* d_in, const int* in_sizes, int n_in,
                              void* d_out, int out_size, void* d_ws, size_t ws_size,
                              hipStream_t stream) {
    const float* x  = (const float*)d_in[0];
    const int*   ei = (const int*)d_in[1];
    const float* W0 = (const float*)d_in[2];
    const float* b0 = (const float*)d_in[3];
    const float* W1 = (const float*)d_in[4];
    const float* b1 = (const float*)d_in[5];
    const float* W2 = (const float*)d_in[6];
    const float* b2 = (const float*)d_in[7];

    const int H = 128;
    int n = in_sizes[0] / H;
    int E = in_sizes[1] / 2;
    const int* srcp = ei;
    const int* dstp = ei + E;

    int gemm_blocks = (n + 127) / 128;
    long npad = (long)gemm_blocks * 128;

    // workspace bump allocator
    char* p = (char*)d_ws;
    auto alloc = [&](size_t bytes) {
        void* r = (void*)p;
        p += (bytes + 255) & ~(size_t)255;
        return r;
    };
    float* bufA = (float*)alloc((size_t)npad * H * sizeof(float));          // 51.25 MB fp32 h
    _Float16* bufH = (_Float16*)alloc((size_t)npad * H * 2);                // 25.6 MB fp16 h
    unsigned short* sh = (unsigned short*)alloc((size_t)npad * H * 2);      // 25.6 MB
    unsigned short* sl = (unsigned short*)alloc((size_t)npad * H * 2);      // 25.6 MB
    unsigned short* Whs = (unsigned short*)alloc(3 * 16384 * 2);
    unsigned short* Wls = (unsigned short*)alloc(3 * 16384 * 2);
    int*  cnt    = (int*)alloc((size_t)n * sizeof(int));
    int*  cursor = (int*)alloc((size_t)n * sizeof(int));
    float* dinv  = (float*)alloc((size_t)n * sizeof(float));
    int*  row    = (int*)alloc((size_t)(n + 1) * sizeof(int));
    int*  part   = (int*)alloc(512 * sizeof(int));
    int*  esrc   = (int*)alloc((size_t)E * sizeof(int));                    // 6.4 MB

    hipMemsetAsync(cnt, 0, (size_t)n * sizeof(int), stream);
    hipMemsetAsync(cursor, 0, (size_t)n * sizeof(int), stream);

    count_kernel<<<(E + TPB - 1) / TPB, TPB, 0, stream>>>(dstp, E, cnt);
    dinv_kernel<<<(n + TPB - 1) / TPB, TPB, 0, stream>>>(cnt, dinv, n);

    int nb = (n + SCAN_TILE - 1) / SCAN_TILE;
    scan_reduce<<<nb, TPB, 0, stream>>>(cnt, part, n);
    scan_part<<<1, 512, 0, stream>>>(part, nb, &row[n]);
    scan_write<<<nb, TPB, 0, stream>>>(cnt, part, row, n);
    scatter_kernel<<<(E + TPB - 1) / TPB, TPB, 0, stream>>>(srcp, dstp, E, row, cursor, esrc);

    wsplit_kernel<<<(3 * 16384 + TPB - 1) / TPB, TPB, 0, stream>>>(W0, W1, W2, Whs, Wls);
    long total4 = (long)n * 32;
    xsplit_kernel<<<(int)((total4 + TPB - 1) / TPB), TPB, 0, stream>>>(x, sh, sl, total4);

    float* out = (float*)d_out;
    int agg_blocks = (n + 15) / 16;
    const h8v* hH = (const h8v*)bufH;

    // layer 0
    gemm_mfma<<<gemm_blocks, 256, 0, stream>>>(sh, sl, Whs, Wls, bufA, bufH, n);
    agg_kernel<true><<<agg_blocks, 256, 0, stream>>>(bufA, hH, dinv, row, esrc, b0, nullptr, sh, sl, n);
    // layer 1
    gemm_mfma<<<gemm_blocks, 256, 0, stream>>>(sh, sl, Whs + 16384, Wls + 16384, bufA, bufH, n);
    agg_kernel<true><<<agg_blocks, 256, 0, stream>>>(bufA, hH, dinv, row, esrc, b1, nullptr, sh, sl, n);
    // layer 2
    gemm_mfma<<<gemm_blocks, 256, 0, stream>>>(sh, sl, Whs + 32768, Wls + 32768, bufA, bufH, n);
    agg_kernel<false><<<agg_blocks, 256, 0, stream>>>(bufA, hH, dinv, row, esrc, b2, out, nullptr, nullptr, n);
}

// Round 5
// 538.203 us; speedup vs baseline: 2.0825x; 1.1018x over previous
//
#include <hip/hip_runtime.h>
#include <hip/hip_bf16.h>

#define TPB 256

typedef short s8v __attribute__((ext_vector_type(8)));     // 8 bf16 in 4 VGPRs
typedef float f4v __attribute__((ext_vector_type(4)));
typedef _Float16 h8v __attribute__((ext_vector_type(8)));  // 8 fp16 in 4 VGPRs

#define PB 64          // buckets
#define BSHIFT 11
#define BSPAN 2048     // nodes per bucket
#define PCHUNK 4096    // edges per partition block

// ---- fp32 -> bf16 split helpers (RNE) ----
__device__ __forceinline__ unsigned short bf16_rne(float v) {
    unsigned int u = __float_as_uint(v);
    u += 0x7fffu + ((u >> 16) & 1u);
    return (unsigned short)(u >> 16);
}
__device__ __forceinline__ void split_bf16(float v, unsigned short& hi, unsigned short& lo) {
    hi = bf16_rne(v);
    float hf = __uint_as_float((unsigned int)hi << 16);
    lo = bf16_rne(v - hf);
}

// ---------------- bucket-partition CSR build ----------------

// B1: bucket sizes via LDS histogram
__global__ __launch_bounds__(256) void bhist_kernel(const int* __restrict__ dst, int E,
                                                    int* __restrict__ bsize) {
    __shared__ int h[PB];
    int t = threadIdx.x;
    if (t < PB) h[t] = 0;
    __syncthreads();
    for (int e = blockIdx.x * 256 + t; e < E; e += gridDim.x * 256)
        atomicAdd(&h[dst[e] >> BSHIFT], 1);
    __syncthreads();
    if (t < PB && h[t] > 0) atomicAdd(&bsize[t], h[t]);
}

// B2: one-wave exclusive scan of 64 bucket sizes
__global__ void bscan_kernel(const int* __restrict__ bsize, int* __restrict__ bbase,
                             int* __restrict__ bcursor, int* __restrict__ row, int n, int E) {
    int t = threadIdx.x;            // 0..63, one wave
    int sz = bsize[t];
    int v = sz;
    for (int off = 1; off < 64; off <<= 1) {
        int u = __shfl_up(v, off);
        if (t >= off) v += u;
    }
    bbase[t + 1] = v;               // inclusive
    bcursor[t] = v - sz;            // exclusive
    if (t == 0) { bbase[0] = 0; row[n] = E; }
}

// B3: partition edges into bucket-contiguous (src,dst) pairs, chunked writes
__global__ __launch_bounds__(256) void partition_kernel(const int* __restrict__ src,
                                                        const int* __restrict__ dst, int E,
                                                        int* __restrict__ bcursor,
                                                        int2* __restrict__ part) {
    __shared__ int h[PB];
    __shared__ int gofs[PB];
    int t = threadIdx.x;
    long base = (long)blockIdx.x * PCHUNK;
    int cnt = (int)min((long)PCHUNK, (long)E - base);

    if (t < PB) h[t] = 0;
    __syncthreads();

    int2 ed[16]; int bk[16]; int nmine = 0;
    for (int j = t; j < cnt; j += 256) {
        int s = src[base + j], d = dst[base + j];
        ed[nmine] = make_int2(s, d);
        int b = d >> BSHIFT;
        bk[nmine] = b;
        atomicAdd(&h[b], 1);
        nmine++;
    }
    __syncthreads();
    if (t < PB) gofs[t] = (h[t] > 0) ? atomicAdd(&bcursor[t], h[t]) : 0;
    __syncthreads();
    if (t < PB) h[t] = 0;           // reuse as local cursor
    __syncthreads();
    for (int j = 0; j < nmine; j++) {
        int b = bk[j];
        int idx = atomicAdd(&h[b], 1);
        part[(long)gofs[b] + idx] = ed[j];
    }
}

// B4: per-bucket degree histogram + scan -> row, dinv; then bucket-local scatter -> esrc
__global__ __launch_bounds__(1024) void csr_kernel(const int2* __restrict__ part,
                                                   const int* __restrict__ bbase,
                                                   int* __restrict__ row, float* __restrict__ dinv,
                                                   int* __restrict__ esrc, int n) {
    __shared__ int deg[BSPAN];
    __shared__ int lrow[BSPAN];
    __shared__ int cur[BSPAN];
    __shared__ int wsum[16];
    int b = blockIdx.x;
    int n0 = b << BSHIFT;
    int nn = min(BSPAN, n - n0);
    if (nn <= 0) return;
    int e0 = bbase[b], e1 = bbase[b + 1];
    int t = threadIdx.x;

    for (int i = t; i < BSPAN; i += 1024) deg[i] = 0;
    __syncthreads();
    for (int e = e0 + t; e < e1; e += 1024)
        atomicAdd(&deg[part[e].y - n0], 1);
    __syncthreads();

    // block exclusive scan of deg[0..2048) -> lrow; 1024 threads x 2 elems
    int i0 = t * 2;
    int a = deg[i0], c = deg[i0 + 1];
    int tsum = a + c;
    int lane = t & 63, wid = t >> 6;
    int v = tsum;
    for (int off = 1; off < 64; off <<= 1) {
        int u = __shfl_up(v, off);
        if (lane >= off) v += u;
    }
    if (lane == 63) wsum[wid] = v;
    __syncthreads();
    if (wid == 0 && lane < 16) {
        int w = wsum[lane];
        for (int off = 1; off < 16; off <<= 1) {
            int u = __shfl_up(w, off);
            if (lane >= off) w += u;
        }
        wsum[lane] = w;
    }
    __syncthreads();
    int excl = v - tsum + ((wid > 0) ? wsum[wid - 1] : 0);
    lrow[i0] = excl;
    lrow[i0 + 1] = excl + a;
    __syncthreads();

    for (int i = t; i < nn; i += 1024) {
        row[n0 + i] = e0 + lrow[i];
        dinv[n0 + i] = rsqrtf((float)(deg[i] + 1));
    }
    for (int i = t; i < BSPAN; i += 1024) cur[i] = 0;
    __syncthreads();

    for (int e = e0 + t; e < e1; e += 1024) {
        int2 p = part[e];
        int d = p.y - n0;
        int idx = atomicAdd(&cur[d], 1);
        esrc[e0 + lrow[d] + idx] = p.x;
    }
}

// ---------------- W / x split ----------------

__global__ void wsplit_kernel(const float* __restrict__ W0, const float* __restrict__ W1,
                              const float* __restrict__ W2,
                              unsigned short* __restrict__ Whi, unsigned short* __restrict__ Wlo) {
    int t = blockIdx.x * TPB + threadIdx.x;           // 0 .. 3*16384
    if (t >= 3 * 16384) return;
    int layer = t >> 14;
    int e = t & 16383;
    int k = e >> 7, ncol = e & 127;
    const float* W = (layer == 0) ? W0 : (layer == 1) ? W1 : W2;
    unsigned short hi, lo;
    split_bf16(W[e], hi, lo);
    int ct = ncol >> 4;
    int lane = (((k >> 3) & 3) << 4) | (ncol & 15);
    int kki = k >> 5;
    int j = k & 7;
    int idx = layer * 16384 + (((ct * 4 + kki) * 64 + lane) * 8 + j);
    Whi[idx] = hi; Wlo[idx] = lo;
}

__global__ void xsplit_kernel(const float* __restrict__ x,
                              unsigned short* __restrict__ xhi, unsigned short* __restrict__ xlo,
                              long total4) {
    long t = (long)blockIdx.x * TPB + threadIdx.x;
    if (t >= total4) return;
    float4 v = ((const float4*)x)[t];
    ushort4 h, l;
    split_bf16(v.x, h.x, l.x); split_bf16(v.y, h.y, l.y);
    split_bf16(v.z, h.z, l.z); split_bf16(v.w, h.w, l.w);
    ((ushort4*)xhi)[t] = h;
    ((ushort4*)xlo)[t] = l;
}

// ---------------- GEMM via split-bf16 MFMA ----------------

__global__ __launch_bounds__(256, 2) void gemm_mfma(const unsigned short* __restrict__ Ahg,
                                                    const unsigned short* __restrict__ Alg,
                                                    const unsigned short* __restrict__ Whs,
                                                    const unsigned short* __restrict__ Wls,
                                                    float* __restrict__ C,
                                                    _Float16* __restrict__ Ch, int n) {
    int t = threadIdx.x;
    int wave = t >> 6, lane = t & 63;
    int ch = wave & 1, rh = wave >> 1;
    int lm = lane & 15, q = lane >> 4;
    long row0 = (long)blockIdx.x * 128 + rh * 64;

    const s8v* Wh8 = (const s8v*)Whs;
    const s8v* Wl8 = (const s8v*)Wls;
    s8v Bh[4][4], Bl[4][4];
#pragma unroll
    for (int ct = 0; ct < 4; ct++)
#pragma unroll
        for (int kki = 0; kki < 4; kki++) {
            int idx = (((ch * 4 + ct) * 4 + kki) * 64) + lane;
            Bh[ct][kki] = Wh8[idx];
            Bl[ct][kki] = Wl8[idx];
        }

    f4v acc[4][4];
#pragma unroll
    for (int rt = 0; rt < 4; rt++)
#pragma unroll
        for (int ct = 0; ct < 4; ct++) acc[rt][ct] = (f4v)0.0f;

    const s8v* A8h = (const s8v*)Ahg;
    const s8v* A8l = (const s8v*)Alg;

#pragma unroll
    for (int kki = 0; kki < 4; kki++) {
        s8v ah[4], al[4];
#pragma unroll
        for (int rt = 0; rt < 4; rt++) {
            long r = row0 + rt * 16 + lm;
            long base = r * 16 + kki * 4 + q;    // units of 8 shorts (16B)
            ah[rt] = A8h[base];
            al[rt] = A8l[base];
        }
#pragma unroll
        for (int rt = 0; rt < 4; rt++)
#pragma unroll
            for (int ct = 0; ct < 4; ct++) {
                acc[rt][ct] = __builtin_amdgcn_mfma_f32_16x16x32_bf16(ah[rt], Bh[ct][kki], acc[rt][ct], 0, 0, 0);
                acc[rt][ct] = __builtin_amdgcn_mfma_f32_16x16x32_bf16(ah[rt], Bl[ct][kki], acc[rt][ct], 0, 0, 0);
                acc[rt][ct] = __builtin_amdgcn_mfma_f32_16x16x32_bf16(al[rt], Bh[ct][kki], acc[rt][ct], 0, 0, 0);
            }
    }

    // C/D layout: col = lane&15 (+tile base), row = (lane>>4)*4 + reg (+tile base)
#pragma unroll
    for (int rt = 0; rt < 4; rt++) {
        long rbase = row0 + rt * 16 + q * 4;
#pragma unroll
        for (int reg = 0; reg < 4; reg++) {
            long r = rbase + reg;
            if (r < n) {
#pragma unroll
                for (int ct = 0; ct < 4; ct++) {
                    float v = acc[rt][ct][reg];
                    long col = ch * 64 + ct * 16 + lm;
                    C[r * 128 + col] = v;
                    Ch[r * 128 + col] = (_Float16)v;
                }
            }
        }
    }
}

// ---------------- aggregation ----------------
// out[i] = relu( sum_e dinv[s]*di*h[s] + di^2*h[i] + b )
// 16 nodes/block; 16 lanes/node, 8 features (16B fp16) per lane.

template <bool SPLIT>
__global__ __launch_bounds__(256) void agg_kernel(const float* __restrict__ hA,
                                                  const h8v* __restrict__ hH,
                                                  const float* __restrict__ dinv,
                                                  const int* __restrict__ row,
                                                  const int* __restrict__ esrc,
                                                  const float* __restrict__ bias,
                                                  float* __restrict__ out,
                                                  unsigned short* __restrict__ ohi,
                                                  unsigned short* __restrict__ olo, int n) {
    int g    = threadIdx.x >> 4;          // node slot 0..15
    int lane = threadIdx.x & 15;          // feature block (8 feats)
    int i = blockIdx.x * 16 + g;
    if (i >= n) return;

    float di = dinv[i];
    float s2 = di * di;

    const float4* a4 = (const float4*)(hA + (size_t)i * 128 + lane * 8);
    float4 sA = a4[0], sB = a4[1];
    float acc[8];
    acc[0] = sA.x * s2; acc[1] = sA.y * s2; acc[2] = sA.z * s2; acc[3] = sA.w * s2;
    acc[4] = sB.x * s2; acc[5] = sB.y * s2; acc[6] = sB.z * s2; acc[7] = sB.w * s2;

    int e0 = row[i], e1 = row[i + 1];
    int e = e0;

    for (; e + 4 <= e1; e += 4) {
        int s0 = esrc[e + 0];
        int s1 = esrc[e + 1];
        int s2i = esrc[e + 2];
        int s3 = esrc[e + 3];
        h8v v0 = hH[(size_t)s0 * 16 + lane];
        h8v v1 = hH[(size_t)s1 * 16 + lane];
        h8v v2 = hH[(size_t)s2i * 16 + lane];
        h8v v3 = hH[(size_t)s3 * 16 + lane];
        float w0 = dinv[s0] * di;
        float w1 = dinv[s1] * di;
        float w2 = dinv[s2i] * di;
        float w3 = dinv[s3] * di;
#pragma unroll
        for (int k = 0; k < 8; k++)
            acc[k] += w0 * (float)v0[k] + w1 * (float)v1[k] + w2 * (float)v2[k] + w3 * (float)v3[k];
    }
    for (; e < e1; ++e) {
        int s = esrc[e];
        h8v v = hH[(size_t)s * 16 + lane];
        float w = dinv[s] * di;
#pragma unroll
        for (int k = 0; k < 8; k++) acc[k] += w * (float)v[k];
    }

    const float4* b4 = (const float4*)(bias + lane * 8);
    float4 bA = b4[0], bB = b4[1];
    float o[8];
    o[0] = fmaxf(acc[0] + bA.x, 0.f); o[1] = fmaxf(acc[1] + bA.y, 0.f);
    o[2] = fmaxf(acc[2] + bA.z, 0.f); o[3] = fmaxf(acc[3] + bA.w, 0.f);
    o[4] = fmaxf(acc[4] + bB.x, 0.f); o[5] = fmaxf(acc[5] + bB.y, 0.f);
    o[6] = fmaxf(acc[6] + bB.z, 0.f); o[7] = fmaxf(acc[7] + bB.w, 0.f);

    if (SPLIT) {
        ushort4 h0, l0, h1, l1;
        split_bf16(o[0], h0.x, l0.x); split_bf16(o[1], h0.y, l0.y);
        split_bf16(o[2], h0.z, l0.z); split_bf16(o[3], h0.w, l0.w);
        split_bf16(o[4], h1.x, l1.x); split_bf16(o[5], h1.y, l1.y);
        split_bf16(o[6], h1.z, l1.z); split_bf16(o[7], h1.w, l1.w);
        ushort4* oh = (ushort4*)(ohi + (size_t)i * 128 + lane * 8);
        ushort4* ol = (ushort4*)(olo + (size_t)i * 128 + lane * 8);
        oh[0] = h0; oh[1] = h1;
        ol[0] = l0; ol[1] = l1;
    } else {
        float4* o4 = (float4*)(out + (size_t)i * 128 + lane * 8);
        o4[0] = make_float4(o[0], o[1], o[2], o[3]);
        o4[1] = make_float4(o[4], o[5], o[6], o[7]);
    }
}

// ---------------- launch ----------------

extern "C" void kernel_launch(void* const* d_in, const int* in_sizes, int n_in,
                              void* d_out, int out_size, void* d_ws, size_t ws_size,
                              hipStream_t stream) {
    const float* x  = (const float*)d_in[0];
    const int*   ei = (const int*)d_in[1];
    const float* W0 = (const float*)d_in[2];
    const float* b0 = (const float*)d_in[3];
    const float* W1 = (const float*)d_in[4];
    const float* b1 = (const float*)d_in[5];
    const float* W2 = (const float*)d_in[6];
    const float* b2 = (const float*)d_in[7];

    const int H = 128;
    int n = in_sizes[0] / H;
    int E = in_sizes[1] / 2;
    const int* srcp = ei;
    const int* dstp = ei + E;

    int gemm_blocks = (n + 127) / 128;
    long npad = (long)gemm_blocks * 128;
    int nbuck = (n + BSPAN - 1) >> BSHIFT;   // <= PB for n <= 131072

    // workspace bump allocator
    char* p = (char*)d_ws;
    auto alloc = [&](size_t bytes) {
        void* r = (void*)p;
        p += (bytes + 255) & ~(size_t)255;
        return r;
    };
    float* bufA = (float*)alloc((size_t)npad * H * sizeof(float));          // 51.25 MB fp32 h
    _Float16* bufH = (_Float16*)alloc((size_t)npad * H * 2);                // 25.6 MB fp16 h
    unsigned short* sh = (unsigned short*)alloc((size_t)npad * H * 2);      // 25.6 MB
    unsigned short* sl = (unsigned short*)alloc((size_t)npad * H * 2);      // 25.6 MB
    unsigned short* Whs = (unsigned short*)alloc(3 * 16384 * 2);
    unsigned short* Wls = (unsigned short*)alloc(3 * 16384 * 2);
    float* dinv  = (float*)alloc((size_t)n * sizeof(float));
    int*  row    = (int*)alloc((size_t)(n + 1) * sizeof(int));
    int*  bsize  = (int*)alloc(PB * sizeof(int));
    int*  bbase  = (int*)alloc((PB + 1) * sizeof(int));
    int*  bcursor= (int*)alloc(PB * sizeof(int));
    int2* part   = (int2*)alloc((size_t)E * sizeof(int2));                  // 12.8 MB
    int*  esrc   = (int*)alloc((size_t)E * sizeof(int));                    // 6.4 MB

    hipMemsetAsync(bsize, 0, PB * sizeof(int), stream);

    bhist_kernel<<<1024, 256, 0, stream>>>(dstp, E, bsize);
    bscan_kernel<<<1, 64, 0, stream>>>(bsize, bbase, bcursor, row, n, E);
    partition_kernel<<<(E + PCHUNK - 1) / PCHUNK, 256, 0, stream>>>(srcp, dstp, E, bcursor, part);
    csr_kernel<<<nbuck, 1024, 0, stream>>>(part, bbase, row, dinv, esrc, n);

    wsplit_kernel<<<(3 * 16384 + TPB - 1) / TPB, TPB, 0, stream>>>(W0, W1, W2, Whs, Wls);
    long total4 = (long)n * 32;
    xsplit_kernel<<<(int)((total4 + TPB - 1) / TPB), TPB, 0, stream>>>(x, sh, sl, total4);

    float* out = (float*)d_out;
    int agg_blocks = (n + 15) / 16;
    const h8v* hH = (const h8v*)bufH;

    // layer 0
    gemm_mfma<<<gemm_blocks, 256, 0, stream>>>(sh, sl, Whs, Wls, bufA, bufH, n);
    agg_kernel<true><<<agg_blocks, 256, 0, stream>>>(bufA, hH, dinv, row, esrc, b0, nullptr, sh, sl, n);
    // layer 1
    gemm_mfma<<<gemm_blocks, 256, 0, stream>>>(sh, sl, Whs + 16384, Wls + 16384, bufA, bufH, n);
    agg_kernel<true><<<agg_blocks, 256, 0, stream>>>(bufA, hH, dinv, row, esrc, b1, nullptr, sh, sl, n);
    // layer 2
    gemm_mfma<<<gemm_blocks, 256, 0, stream>>>(sh, sl, Whs + 32768, Wls + 32768, bufA, bufH, n);
    agg_kernel<false><<<agg_blocks, 256, 0, stream>>>(bufA, hH, dinv, row, esrc, b2, out, nullptr, nullptr, n);
}

// Round 6
// 462.687 us; speedup vs baseline: 2.4224x; 1.1632x over previous
//
#include <hip/hip_runtime.h>
#include <hip/hip_bf16.h>

#define TPB 256

typedef short s8v __attribute__((ext_vector_type(8)));     // 8 bf16 in 4 VGPRs
typedef float f4v __attribute__((ext_vector_type(4)));
typedef _Float16 h8v __attribute__((ext_vector_type(8)));  // 8 fp16 in 4 VGPRs

#define PB 128         // buckets
#define BSHIFT 10
#define BSPAN 1024     // nodes per bucket
#define PCHUNK 4096    // edges per partition block

// ---- fp32 -> bf16 split helpers (RNE) ----
__device__ __forceinline__ unsigned short bf16_rne(float v) {
    unsigned int u = __float_as_uint(v);
    u += 0x7fffu + ((u >> 16) & 1u);
    return (unsigned short)(u >> 16);
}
__device__ __forceinline__ void split_bf16(float v, unsigned short& hi, unsigned short& lo) {
    hi = bf16_rne(v);
    float hf = __uint_as_float((unsigned int)hi << 16);
    lo = bf16_rne(v - hf);
}

// ---------------- bucket-partition CSR build ----------------

// B1: bucket sizes via LDS histogram
__global__ __launch_bounds__(256) void bhist_kernel(const int* __restrict__ dst, int E,
                                                    int* __restrict__ bsize) {
    __shared__ int h[PB];
    int t = threadIdx.x;
    if (t < PB) h[t] = 0;
    __syncthreads();
    for (int e = blockIdx.x * 256 + t; e < E; e += gridDim.x * 256)
        atomicAdd(&h[dst[e] >> BSHIFT], 1);
    __syncthreads();
    if (t < PB && h[t] > 0) atomicAdd(&bsize[t], h[t]);
}

// B2: 128-thread exclusive scan of bucket sizes
__global__ void bscan_kernel(const int* __restrict__ bsize, int* __restrict__ bbase,
                             int* __restrict__ bcursor, int* __restrict__ row, int n, int E) {
    __shared__ int wtot[2];
    int t = threadIdx.x;            // 0..127
    int sz = bsize[t];
    int lane = t & 63, wid = t >> 6;
    int v = sz;
    for (int off = 1; off < 64; off <<= 1) {
        int u = __shfl_up(v, off);
        if (lane >= off) v += u;
    }
    if (lane == 63) wtot[wid] = v;
    __syncthreads();
    if (wid == 1) v += wtot[0];
    bbase[t + 1] = v;               // inclusive
    bcursor[t] = v - sz;            // exclusive
    if (t == 0) { bbase[0] = 0; row[n] = E; }
}

// B3: partition edges into bucket-contiguous (src,dst); two passes over L2-hot chunk
__global__ __launch_bounds__(256) void partition_kernel(const int* __restrict__ src,
                                                        const int* __restrict__ dst, int E,
                                                        int* __restrict__ bcursor,
                                                        int2* __restrict__ part) {
    __shared__ int h[PB];
    __shared__ int gofs[PB];
    int t = threadIdx.x;
    long base = (long)blockIdx.x * PCHUNK;
    int cnt = (int)min((long)PCHUNK, (long)E - base);

    if (t < PB) h[t] = 0;
    __syncthreads();
    for (int j = t; j < cnt; j += 256)
        atomicAdd(&h[dst[base + j] >> BSHIFT], 1);
    __syncthreads();
    if (t < PB) gofs[t] = (h[t] > 0) ? atomicAdd(&bcursor[t], h[t]) : 0;
    __syncthreads();
    if (t < PB) h[t] = 0;           // reuse as local cursor
    __syncthreads();
    for (int j = t; j < cnt; j += 256) {
        int s = src[base + j], d = dst[base + j];   // re-read: L2-hot
        int b = d >> BSHIFT;
        int idx = atomicAdd(&h[b], 1);
        part[(long)gofs[b] + idx] = make_int2(s, d);
    }
}

// B4: per-bucket degree histogram + scan -> row, dinv; bucket-local scatter -> esrc
__global__ __launch_bounds__(1024) void csr_kernel(const int2* __restrict__ part,
                                                   const int* __restrict__ bbase,
                                                   int* __restrict__ row, float* __restrict__ dinv,
                                                   int* __restrict__ esrc, int n) {
    __shared__ int deg[BSPAN];
    __shared__ int lrow[BSPAN];
    __shared__ int cur[BSPAN];
    __shared__ int wsum[16];
    int b = blockIdx.x;
    int n0 = b << BSHIFT;
    int nn = min(BSPAN, n - n0);
    if (nn <= 0) return;
    int e0 = bbase[b], e1 = bbase[b + 1];
    int t = threadIdx.x;

    deg[t] = 0;
    __syncthreads();
    for (int e = e0 + t; e < e1; e += 1024)
        atomicAdd(&deg[part[e].y - n0], 1);
    __syncthreads();

    // block exclusive scan of deg[0..1024), 1 elem/thread
    int a = deg[t];
    int lane = t & 63, wid = t >> 6;
    int v = a;
    for (int off = 1; off < 64; off <<= 1) {
        int u = __shfl_up(v, off);
        if (lane >= off) v += u;
    }
    if (lane == 63) wsum[wid] = v;
    __syncthreads();
    if (wid == 0 && lane < 16) {
        int w = wsum[lane];
        for (int off = 1; off < 16; off <<= 1) {
            int u = __shfl_up(w, off);
            if (lane >= off) w += u;
        }
        wsum[lane] = w;
    }
    __syncthreads();
    int excl = v - a + ((wid > 0) ? wsum[wid - 1] : 0);
    lrow[t] = excl;
    cur[t] = 0;
    if (t < nn) {
        row[n0 + t] = e0 + excl;
        dinv[n0 + t] = rsqrtf((float)(deg[t] + 1));
    }
    __syncthreads();

    for (int e = e0 + t; e < e1; e += 1024) {
        int2 p = part[e];
        int d = p.y - n0;
        int idx = atomicAdd(&cur[d], 1);
        esrc[e0 + lrow[d] + idx] = p.x;
    }
}

// ---------------- W split ----------------

__global__ void wsplit_kernel(const float* __restrict__ W0, const float* __restrict__ W1,
                              const float* __restrict__ W2,
                              unsigned short* __restrict__ Whi, unsigned short* __restrict__ Wlo) {
    int t = blockIdx.x * TPB + threadIdx.x;           // 0 .. 3*16384
    if (t >= 3 * 16384) return;
    int layer = t >> 14;
    int e = t & 16383;
    int k = e >> 7, ncol = e & 127;
    const float* W = (layer == 0) ? W0 : (layer == 1) ? W1 : W2;
    unsigned short hi, lo;
    split_bf16(W[e], hi, lo);
    int ct = ncol >> 4;
    int lane = (((k >> 3) & 3) << 4) | (ncol & 15);
    int kki = k >> 5;
    int j = k & 7;
    int idx = layer * 16384 + (((ct * 4 + kki) * 64 + lane) * 8 + j);
    Whi[idx] = hi; Wlo[idx] = lo;
}

// ---------------- GEMM via split-bf16 MFMA ----------------
// C[n,128] = A[n,128] @ W[128,128]; writes fp16 Ch only.
// F32IN=true: A read as fp32 and split on the fly (layer 0); else hi/lo bf16 arrays.

template <bool F32IN>
__global__ __launch_bounds__(256, 2) void gemm_mfma(const float* __restrict__ Xf,
                                                    const unsigned short* __restrict__ Ahg,
                                                    const unsigned short* __restrict__ Alg,
                                                    const unsigned short* __restrict__ Whs,
                                                    const unsigned short* __restrict__ Wls,
                                                    _Float16* __restrict__ Ch, int n) {
    int t = threadIdx.x;
    int wave = t >> 6, lane = t & 63;
    int ch = wave & 1, rh = wave >> 1;
    int lm = lane & 15, q = lane >> 4;
    long row0 = (long)blockIdx.x * 128 + rh * 64;

    const s8v* Wh8 = (const s8v*)Whs;
    const s8v* Wl8 = (const s8v*)Wls;
    s8v Bh[4][4], Bl[4][4];
#pragma unroll
    for (int ct = 0; ct < 4; ct++)
#pragma unroll
        for (int kki = 0; kki < 4; kki++) {
            int idx = (((ch * 4 + ct) * 4 + kki) * 64) + lane;
            Bh[ct][kki] = Wh8[idx];
            Bl[ct][kki] = Wl8[idx];
        }

    f4v acc[4][4];
#pragma unroll
    for (int rt = 0; rt < 4; rt++)
#pragma unroll
        for (int ct = 0; ct < 4; ct++) acc[rt][ct] = (f4v)0.0f;

    const s8v* A8h = (const s8v*)Ahg;
    const s8v* A8l = (const s8v*)Alg;

#pragma unroll
    for (int kki = 0; kki < 4; kki++) {
        s8v ah[4], al[4];
#pragma unroll
        for (int rt = 0; rt < 4; rt++) {
            long r = row0 + rt * 16 + lm;
            if (F32IN) {
                long rr = (r < n) ? r : (n - 1);   // clamp: padded rows unused
                const float4* xf4 = (const float4*)(Xf + rr * 128 + kki * 32 + q * 8);
                float4 u0 = xf4[0], u1 = xf4[1];
                float uf[8] = {u0.x, u0.y, u0.z, u0.w, u1.x, u1.y, u1.z, u1.w};
                s8v hv, lv;
#pragma unroll
                for (int j = 0; j < 8; j++) {
                    unsigned short hh, ll;
                    split_bf16(uf[j], hh, ll);
                    hv[j] = (short)hh; lv[j] = (short)ll;
                }
                ah[rt] = hv; al[rt] = lv;
            } else {
                long base = r * 16 + kki * 4 + q;    // units of 8 shorts (16B)
                ah[rt] = A8h[base];
                al[rt] = A8l[base];
            }
        }
#pragma unroll
        for (int rt = 0; rt < 4; rt++)
#pragma unroll
            for (int ct = 0; ct < 4; ct++) {
                acc[rt][ct] = __builtin_amdgcn_mfma_f32_16x16x32_bf16(ah[rt], Bh[ct][kki], acc[rt][ct], 0, 0, 0);
                acc[rt][ct] = __builtin_amdgcn_mfma_f32_16x16x32_bf16(ah[rt], Bl[ct][kki], acc[rt][ct], 0, 0, 0);
                acc[rt][ct] = __builtin_amdgcn_mfma_f32_16x16x32_bf16(al[rt], Bh[ct][kki], acc[rt][ct], 0, 0, 0);
            }
    }

    // C/D layout: col = lane&15 (+tile base), row = (lane>>4)*4 + reg (+tile base)
#pragma unroll
    for (int rt = 0; rt < 4; rt++) {
        long rbase = row0 + rt * 16 + q * 4;
#pragma unroll
        for (int reg = 0; reg < 4; reg++) {
            long r = rbase + reg;
            if (r < n) {
#pragma unroll
                for (int ct = 0; ct < 4; ct++)
                    Ch[r * 128 + ch * 64 + ct * 16 + lm] = (_Float16)acc[rt][ct][reg];
            }
        }
    }
}

// ---------------- aggregation ----------------
// out[i] = relu( sum_e dinv[s]*di*h[s] + di^2*h[i] + b ), h in fp16.
// 16 nodes/block; 16 lanes/node, 8 features (16B fp16) per lane.

template <bool SPLIT>
__global__ __launch_bounds__(256) void agg_kernel(const h8v* __restrict__ hH,
                                                  const float* __restrict__ dinv,
                                                  const int* __restrict__ row,
                                                  const int* __restrict__ esrc,
                                                  const float* __restrict__ bias,
                                                  float* __restrict__ out,
                                                  unsigned short* __restrict__ ohi,
                                                  unsigned short* __restrict__ olo, int n) {
    int g    = threadIdx.x >> 4;          // node slot 0..15
    int lane = threadIdx.x & 15;          // feature block (8 feats)
    int i = blockIdx.x * 16 + g;
    if (i >= n) return;

    float di = dinv[i];
    float s2 = di * di;

    h8v self = hH[(size_t)i * 16 + lane];
    float acc[8];
#pragma unroll
    for (int k = 0; k < 8; k++) acc[k] = (float)self[k] * s2;

    int e0 = row[i], e1 = row[i + 1];
    int e = e0;

    for (; e + 4 <= e1; e += 4) {
        int s0 = esrc[e + 0];
        int s1 = esrc[e + 1];
        int s2i = esrc[e + 2];
        int s3 = esrc[e + 3];
        h8v v0 = hH[(size_t)s0 * 16 + lane];
        h8v v1 = hH[(size_t)s1 * 16 + lane];
        h8v v2 = hH[(size_t)s2i * 16 + lane];
        h8v v3 = hH[(size_t)s3 * 16 + lane];
        float w0 = dinv[s0] * di;
        float w1 = dinv[s1] * di;
        float w2 = dinv[s2i] * di;
        float w3 = dinv[s3] * di;
#pragma unroll
        for (int k = 0; k < 8; k++)
            acc[k] += w0 * (float)v0[k] + w1 * (float)v1[k] + w2 * (float)v2[k] + w3 * (float)v3[k];
    }
    for (; e < e1; ++e) {
        int s = esrc[e];
        h8v v = hH[(size_t)s * 16 + lane];
        float w = dinv[s] * di;
#pragma unroll
        for (int k = 0; k < 8; k++) acc[k] += w * (float)v[k];
    }

    const float4* b4 = (const float4*)(bias + lane * 8);
    float4 bA = b4[0], bB = b4[1];
    float o[8];
    o[0] = fmaxf(acc[0] + bA.x, 0.f); o[1] = fmaxf(acc[1] + bA.y, 0.f);
    o[2] = fmaxf(acc[2] + bA.z, 0.f); o[3] = fmaxf(acc[3] + bA.w, 0.f);
    o[4] = fmaxf(acc[4] + bB.x, 0.f); o[5] = fmaxf(acc[5] + bB.y, 0.f);
    o[6] = fmaxf(acc[6] + bB.z, 0.f); o[7] = fmaxf(acc[7] + bB.w, 0.f);

    if (SPLIT) {
        ushort4 h0, l0, h1, l1;
        split_bf16(o[0], h0.x, l0.x); split_bf16(o[1], h0.y, l0.y);
        split_bf16(o[2], h0.z, l0.z); split_bf16(o[3], h0.w, l0.w);
        split_bf16(o[4], h1.x, l1.x); split_bf16(o[5], h1.y, l1.y);
        split_bf16(o[6], h1.z, l1.z); split_bf16(o[7], h1.w, l1.w);
        ushort4* oh = (ushort4*)(ohi + (size_t)i * 128 + lane * 8);
        ushort4* ol = (ushort4*)(olo + (size_t)i * 128 + lane * 8);
        oh[0] = h0; oh[1] = h1;
        ol[0] = l0; ol[1] = l1;
    } else {
        float4* o4 = (float4*)(out + (size_t)i * 128 + lane * 8);
        o4[0] = make_float4(o[0], o[1], o[2], o[3]);
        o4[1] = make_float4(o[4], o[5], o[6], o[7]);
    }
}

// ---------------- launch ----------------

extern "C" void kernel_launch(void* const* d_in, const int* in_sizes, int n_in,
                              void* d_out, int out_size, void* d_ws, size_t ws_size,
                              hipStream_t stream) {
    const float* x  = (const float*)d_in[0];
    const int*   ei = (const int*)d_in[1];
    const float* W0 = (const float*)d_in[2];
    const float* b0 = (const float*)d_in[3];
    const float* W1 = (const float*)d_in[4];
    const float* b1 = (const float*)d_in[5];
    const float* W2 = (const float*)d_in[6];
    const float* b2 = (const float*)d_in[7];

    const int H = 128;
    int n = in_sizes[0] / H;
    int E = in_sizes[1] / 2;
    const int* srcp = ei;
    const int* dstp = ei + E;

    int gemm_blocks = (n + 127) / 128;
    long npad = (long)gemm_blocks * 128;
    int nbuck = (n + BSPAN - 1) >> BSHIFT;   // <= PB for n <= 131072

    // workspace bump allocator
    char* p = (char*)d_ws;
    auto alloc = [&](size_t bytes) {
        void* r = (void*)p;
        p += (bytes + 255) & ~(size_t)255;
        return r;
    };
    _Float16* bufH = (_Float16*)alloc((size_t)npad * H * 2);                // 25.6 MB fp16 h
    unsigned short* sh = (unsigned short*)alloc((size_t)npad * H * 2);      // 25.6 MB
    unsigned short* sl = (unsigned short*)alloc((size_t)npad * H * 2);      // 25.6 MB
    unsigned short* Whs = (unsigned short*)alloc(3 * 16384 * 2);
    unsigned short* Wls = (unsigned short*)alloc(3 * 16384 * 2);
    float* dinv  = (float*)alloc((size_t)n * sizeof(float));
    int*  row    = (int*)alloc((size_t)(n + 1) * sizeof(int));
    int*  bsize  = (int*)alloc(PB * sizeof(int));
    int*  bbase  = (int*)alloc((PB + 1) * sizeof(int));
    int*  bcursor= (int*)alloc(PB * sizeof(int));
    int2* part   = (int2*)alloc((size_t)E * sizeof(int2));                  // 12.8 MB
    int*  esrc   = (int*)alloc((size_t)E * sizeof(int));                    // 6.4 MB

    hipMemsetAsync(bsize, 0, PB * sizeof(int), stream);

    bhist_kernel<<<1024, 256, 0, stream>>>(dstp, E, bsize);
    bscan_kernel<<<1, PB, 0, stream>>>(bsize, bbase, bcursor, row, n, E);
    partition_kernel<<<(E + PCHUNK - 1) / PCHUNK, 256, 0, stream>>>(srcp, dstp, E, bcursor, part);
    csr_kernel<<<nbuck, 1024, 0, stream>>>(part, bbase, row, dinv, esrc, n);

    wsplit_kernel<<<(3 * 16384 + TPB - 1) / TPB, TPB, 0, stream>>>(W0, W1, W2, Whs, Wls);

    float* out = (float*)d_out;
    int agg_blocks = (n + 15) / 16;
    const h8v* hH = (const h8v*)bufH;

    // layer 0 (gemm reads fp32 x directly, splits on the fly)
    gemm_mfma<true><<<gemm_blocks, 256, 0, stream>>>(x, nullptr, nullptr, Whs, Wls, bufH, n);
    agg_kernel<true><<<agg_blocks, 256, 0, stream>>>(hH, dinv, row, esrc, b0, nullptr, sh, sl, n);
    // layer 1
    gemm_mfma<false><<<gemm_blocks, 256, 0, stream>>>(nullptr, sh, sl, Whs + 16384, Wls + 16384, bufH, n);
    agg_kernel<true><<<agg_blocks, 256, 0, stream>>>(hH, dinv, row, esrc, b1, nullptr, sh, sl, n);
    // layer 2
    gemm_mfma<false><<<gemm_blocks, 256, 0, stream>>>(nullptr, sh, sl, Whs + 32768, Wls + 32768, bufH, n);
    agg_kernel<false><<<agg_blocks, 256, 0, stream>>>(hH, dinv, row, esrc, b2, out, nullptr, nullptr, n);
}

// Round 8
// 409.457 us; speedup vs baseline: 2.7373x; 1.1300x over previous
//
#include <hip/hip_runtime.h>
#include <hip/hip_bf16.h>

#define TPB 256

typedef short s8v __attribute__((ext_vector_type(8)));     // 8 bf16 in 4 VGPRs
typedef float f4v __attribute__((ext_vector_type(4)));
typedef _Float16 h8v __attribute__((ext_vector_type(8)));  // 8 fp16 in 4 VGPRs

#define PB 128         // buckets
#define BSHIFT 10
#define BSPAN 1024     // nodes per bucket
#define PCHUNK 4096    // edges per partition block

// ---- fp32 -> bf16 split helpers (RNE) ----
__device__ __forceinline__ unsigned short bf16_rne(float v) {
    unsigned int u = __float_as_uint(v);
    u += 0x7fffu + ((u >> 16) & 1u);
    return (unsigned short)(u >> 16);
}
__device__ __forceinline__ void split_bf16(float v, unsigned short& hi, unsigned short& lo) {
    hi = bf16_rne(v);
    float hf = __uint_as_float((unsigned int)hi << 16);
    lo = bf16_rne(v - hf);
}

// ---------------- bucket-partition CSR build ----------------

__global__ __launch_bounds__(256) void bhist_kernel(const int* __restrict__ dst, int E,
                                                    int* __restrict__ bsize) {
    __shared__ int h[PB];
    int t = threadIdx.x;
    if (t < PB) h[t] = 0;
    __syncthreads();
    for (int e = blockIdx.x * 256 + t; e < E; e += gridDim.x * 256)
        atomicAdd(&h[dst[e] >> BSHIFT], 1);
    __syncthreads();
    if (t < PB && h[t] > 0) atomicAdd(&bsize[t], h[t]);
}

__global__ void bscan_kernel(const int* __restrict__ bsize, int* __restrict__ bbase,
                             int* __restrict__ bcursor, int* __restrict__ row, int n, int E) {
    __shared__ int wtot[2];
    int t = threadIdx.x;            // 0..127
    int sz = bsize[t];
    int lane = t & 63, wid = t >> 6;
    int v = sz;
    for (int off = 1; off < 64; off <<= 1) {
        int u = __shfl_up(v, off);
        if (lane >= off) v += u;
    }
    if (lane == 63) wtot[wid] = v;
    __syncthreads();
    if (wid == 1) v += wtot[0];
    bbase[t + 1] = v;               // inclusive
    bcursor[t] = v - sz;            // exclusive
    if (t == 0) { bbase[0] = 0; row[n] = E; }
}

__global__ __launch_bounds__(256) void partition_kernel(const int* __restrict__ src,
                                                        const int* __restrict__ dst, int E,
                                                        int* __restrict__ bcursor,
                                                        int2* __restrict__ part) {
    __shared__ int h[PB];
    __shared__ int gofs[PB];
    int t = threadIdx.x;
    long base = (long)blockIdx.x * PCHUNK;
    int cnt = (int)min((long)PCHUNK, (long)E - base);

    if (t < PB) h[t] = 0;
    __syncthreads();
    for (int j = t; j < cnt; j += 256)
        atomicAdd(&h[dst[base + j] >> BSHIFT], 1);
    __syncthreads();
    if (t < PB) gofs[t] = (h[t] > 0) ? atomicAdd(&bcursor[t], h[t]) : 0;
    __syncthreads();
    if (t < PB) h[t] = 0;           // reuse as local cursor
    __syncthreads();
    for (int j = t; j < cnt; j += 256) {
        int s = src[base + j], d = dst[base + j];   // re-read: L2-hot
        int b = d >> BSHIFT;
        int idx = atomicAdd(&h[b], 1);
        part[(long)gofs[b] + idx] = make_int2(s, d);
    }
}

__global__ __launch_bounds__(1024) void csr_kernel(const int2* __restrict__ part,
                                                   const int* __restrict__ bbase,
                                                   int* __restrict__ row, float* __restrict__ dinv,
                                                   int* __restrict__ esrc, int n) {
    __shared__ int deg[BSPAN];
    __shared__ int lrow[BSPAN];
    __shared__ int cur[BSPAN];
    __shared__ int wsum[16];
    int b = blockIdx.x;
    int n0 = b << BSHIFT;
    int nn = min(BSPAN, n - n0);
    if (nn <= 0) return;
    int e0 = bbase[b], e1 = bbase[b + 1];
    int t = threadIdx.x;

    deg[t] = 0;
    __syncthreads();
    for (int e = e0 + t; e < e1; e += 1024)
        atomicAdd(&deg[part[e].y - n0], 1);
    __syncthreads();

    int a = deg[t];
    int lane = t & 63, wid = t >> 6;
    int v = a;
    for (int off = 1; off < 64; off <<= 1) {
        int u = __shfl_up(v, off);
        if (lane >= off) v += u;
    }
    if (lane == 63) wsum[wid] = v;
    __syncthreads();
    if (wid == 0 && lane < 16) {
        int w = wsum[lane];
        for (int off = 1; off < 16; off <<= 1) {
            int u = __shfl_up(w, off);
            if (lane >= off) w += u;
        }
        wsum[lane] = w;
    }
    __syncthreads();
    int excl = v - a + ((wid > 0) ? wsum[wid - 1] : 0);
    lrow[t] = excl;
    cur[t] = 0;
    if (t < nn) {
        row[n0 + t] = e0 + excl;
        dinv[n0 + t] = rsqrtf((float)(deg[t] + 1));
    }
    __syncthreads();

    for (int e = e0 + t; e < e1; e += 1024) {
        int2 p = part[e];
        int d = p.y - n0;
        int idx = atomicAdd(&cur[d], 1);
        esrc[e0 + lrow[d] + idx] = p.x;
    }
}

// ---------------- W split ----------------

__global__ void wsplit_kernel(const float* __restrict__ W0, const float* __restrict__ W1,
                              const float* __restrict__ W2,
                              unsigned short* __restrict__ Whi, unsigned short* __restrict__ Wlo) {
    int t = blockIdx.x * TPB + threadIdx.x;           // 0 .. 3*16384
    if (t >= 3 * 16384) return;
    int layer = t >> 14;
    int e = t & 16383;
    int k = e >> 7, ncol = e & 127;
    const float* W = (layer == 0) ? W0 : (layer == 1) ? W1 : W2;
    unsigned short hi, lo;
    split_bf16(W[e], hi, lo);
    int ct = ncol >> 4;
    int lane = (((k >> 3) & 3) << 4) | (ncol & 15);
    int kki = k >> 5;
    int j = k & 7;
    int idx = layer * 16384 + (((ct * 4 + kki) * 64 + lane) * 8 + j);
    Whi[idx] = hi; Wlo[idx] = lo;
}

// ---------------- layer-0 GEMM: h0 = x @ W0 (fp16 out, LDS-repacked stores) ----------------

__global__ __launch_bounds__(256, 2) void gemm0_mfma(const float* __restrict__ Xf,
                                                     const unsigned short* __restrict__ Whs,
                                                     const unsigned short* __restrict__ Wls,
                                                     _Float16* __restrict__ Ch, int n) {
    __shared__ _Float16 Oh[128 * 128];
    int t = threadIdx.x;
    int wave = t >> 6, lane = t & 63;
    int ch = wave & 1, rh = wave >> 1;
    int lm = lane & 15, q = lane >> 4;
    long row0 = (long)blockIdx.x * 128 + rh * 64;

    const s8v* Wh8 = (const s8v*)Whs;
    const s8v* Wl8 = (const s8v*)Wls;
    s8v Bh[4][4], Bl[4][4];
#pragma unroll
    for (int ct = 0; ct < 4; ct++)
#pragma unroll
        for (int kki = 0; kki < 4; kki++) {
            int idx = (((ch * 4 + ct) * 4 + kki) * 64) + lane;
            Bh[ct][kki] = Wh8[idx];
            Bl[ct][kki] = Wl8[idx];
        }

    f4v acc[4][4];
#pragma unroll
    for (int rt = 0; rt < 4; rt++)
#pragma unroll
        for (int ct = 0; ct < 4; ct++) acc[rt][ct] = (f4v)0.0f;

#pragma unroll
    for (int kki = 0; kki < 4; kki++) {
        s8v ah[4], al[4];
#pragma unroll
        for (int rt = 0; rt < 4; rt++) {
            long r = row0 + rt * 16 + lm;
            long rr = (r < n) ? r : (n - 1);   // clamp: padded rows discarded
            const float4* xf4 = (const float4*)(Xf + rr * 128 + kki * 32 + q * 8);
            float4 u0 = xf4[0], u1 = xf4[1];
            float uf[8] = {u0.x, u0.y, u0.z, u0.w, u1.x, u1.y, u1.z, u1.w};
            s8v hv, lv;
#pragma unroll
            for (int j = 0; j < 8; j++) {
                unsigned short hh, ll;
                split_bf16(uf[j], hh, ll);
                hv[j] = (short)hh; lv[j] = (short)ll;
            }
            ah[rt] = hv; al[rt] = lv;
        }
#pragma unroll
        for (int rt = 0; rt < 4; rt++)
#pragma unroll
            for (int ct = 0; ct < 4; ct++) {
                acc[rt][ct] = __builtin_amdgcn_mfma_f32_16x16x32_bf16(ah[rt], Bh[ct][kki], acc[rt][ct], 0, 0, 0);
                acc[rt][ct] = __builtin_amdgcn_mfma_f32_16x16x32_bf16(ah[rt], Bl[ct][kki], acc[rt][ct], 0, 0, 0);
                acc[rt][ct] = __builtin_amdgcn_mfma_f32_16x16x32_bf16(al[rt], Bh[ct][kki], acc[rt][ct], 0, 0, 0);
            }
    }

    // stage fp16 tile in LDS, then coalesced 16B stores
#pragma unroll
    for (int rt = 0; rt < 4; rt++)
#pragma unroll
        for (int reg = 0; reg < 4; reg++) {
            int lr = rh * 64 + rt * 16 + q * 4 + reg;
#pragma unroll
            for (int ct = 0; ct < 4; ct++)
                Oh[lr * 128 + ch * 64 + ct * 16 + lm] = (_Float16)acc[rt][ct][reg];
        }
    __syncthreads();

    long rowb = (long)blockIdx.x * 128;
    int lr = t >> 1;                    // local row
    int cb = (t & 1) * 64;              // col base (64 halves = 8 uint4 per thread)
    if (rowb + lr < n) {
        const uint4* s = (const uint4*)&Oh[lr * 128 + cb];
        uint4* d = (uint4*)&Ch[(rowb + lr) * 128 + cb];
#pragma unroll
        for (int u = 0; u < 8; u++) d[u] = s[u];   // FIX: was u<4 — half the cols stayed poison
    }
}

// ---------------- fused agg + next-layer GEMM ----------------
// r = relu( sum_e dinv[s]*di*hIn[s] + di^2*hIn[i] + b );  hOut = fp16( r @ Wnext )
// 256 thr = 16 nodes; gather: 16 lanes/node x 8 feats. GEMM: 16x128 @ 128x128 via MFMA.

__global__ __launch_bounds__(256) void fused_kernel(const h8v* __restrict__ hIn,
                                                    const float* __restrict__ dinv,
                                                    const int* __restrict__ row,
                                                    const int* __restrict__ esrc,
                                                    const float* __restrict__ bias,
                                                    const unsigned short* __restrict__ Whs,
                                                    const unsigned short* __restrict__ Wls,
                                                    _Float16* __restrict__ hOut, int n) {
    __shared__ float As[16 * 132];   // padded stride 132; reused as fp16 out-stage
    int t = threadIdx.x;
    int g = t >> 4, lane = t & 15;
    long i = (long)blockIdx.x * 16 + g;

    float r[8];
    if (i < n) {
        float di = dinv[i];
        float s2 = di * di;
        h8v self = hIn[i * 16 + lane];
        float acc[8];
#pragma unroll
        for (int k = 0; k < 8; k++) acc[k] = (float)self[k] * s2;

        int e0 = row[i], e1 = row[i + 1];
        int e = e0;
        for (; e + 4 <= e1; e += 4) {
            int s0 = esrc[e + 0];
            int s1 = esrc[e + 1];
            int s2i = esrc[e + 2];
            int s3 = esrc[e + 3];
            h8v v0 = hIn[(size_t)s0 * 16 + lane];
            h8v v1 = hIn[(size_t)s1 * 16 + lane];
            h8v v2 = hIn[(size_t)s2i * 16 + lane];
            h8v v3 = hIn[(size_t)s3 * 16 + lane];
            float w0 = dinv[s0] * di;
            float w1 = dinv[s1] * di;
            float w2 = dinv[s2i] * di;
            float w3 = dinv[s3] * di;
#pragma unroll
            for (int k = 0; k < 8; k++)
                acc[k] += w0 * (float)v0[k] + w1 * (float)v1[k] + w2 * (float)v2[k] + w3 * (float)v3[k];
        }
        for (; e < e1; ++e) {
            int s = esrc[e];
            h8v v = hIn[(size_t)s * 16 + lane];
            float w = dinv[s] * di;
#pragma unroll
            for (int k = 0; k < 8; k++) acc[k] += w * (float)v[k];
        }

        const float4* b4 = (const float4*)(bias + lane * 8);
        float4 bA = b4[0], bB = b4[1];
        r[0] = fmaxf(acc[0] + bA.x, 0.f); r[1] = fmaxf(acc[1] + bA.y, 0.f);
        r[2] = fmaxf(acc[2] + bA.z, 0.f); r[3] = fmaxf(acc[3] + bA.w, 0.f);
        r[4] = fmaxf(acc[4] + bB.x, 0.f); r[5] = fmaxf(acc[5] + bB.y, 0.f);
        r[6] = fmaxf(acc[6] + bB.z, 0.f); r[7] = fmaxf(acc[7] + bB.w, 0.f);
    } else {
#pragma unroll
        for (int k = 0; k < 8; k++) r[k] = 0.f;
    }

    float* dstA = &As[g * 132 + lane * 8];
    *(float4*)dstA = make_float4(r[0], r[1], r[2], r[3]);
    *(float4*)(dstA + 4) = make_float4(r[4], r[5], r[6], r[7]);
    __syncthreads();

    // GEMM phase: wave w handles cols [w*32, w*32+32)
    int w = t >> 6, l64 = t & 63;
    int lm = l64 & 15, q = l64 >> 4;

    const s8v* Wh8 = (const s8v*)Whs;
    const s8v* Wl8 = (const s8v*)Wls;
    s8v Bh[2][4], Bl[2][4];
#pragma unroll
    for (int c = 0; c < 2; c++)
#pragma unroll
        for (int kki = 0; kki < 4; kki++) {
            int idx = (((w * 2 + c) * 4 + kki) * 64) + l64;
            Bh[c][kki] = Wh8[idx];
            Bl[c][kki] = Wl8[idx];
        }

    f4v acc2[2];
    acc2[0] = (f4v)0.0f; acc2[1] = (f4v)0.0f;

#pragma unroll
    for (int kki = 0; kki < 4; kki++) {
        const float* ap = &As[lm * 132 + kki * 32 + q * 8];
        float4 u0 = *(const float4*)ap;
        float4 u1 = *(const float4*)(ap + 4);
        float uf[8] = {u0.x, u0.y, u0.z, u0.w, u1.x, u1.y, u1.z, u1.w};
        s8v hv, lv;
#pragma unroll
        for (int j = 0; j < 8; j++) {
            unsigned short hh, ll;
            split_bf16(uf[j], hh, ll);
            hv[j] = (short)hh; lv[j] = (short)ll;
        }
#pragma unroll
        for (int c = 0; c < 2; c++) {
            acc2[c] = __builtin_amdgcn_mfma_f32_16x16x32_bf16(hv, Bh[c][kki], acc2[c], 0, 0, 0);
            acc2[c] = __builtin_amdgcn_mfma_f32_16x16x32_bf16(hv, Bl[c][kki], acc2[c], 0, 0, 0);
            acc2[c] = __builtin_amdgcn_mfma_f32_16x16x32_bf16(lv, Bh[c][kki], acc2[c], 0, 0, 0);
        }
    }
    __syncthreads();

    _Float16* Oh = (_Float16*)As;
#pragma unroll
    for (int c = 0; c < 2; c++)
#pragma unroll
        for (int reg = 0; reg < 4; reg++)
            Oh[(q * 4 + reg) * 128 + (w * 2 + c) * 16 + lm] = (_Float16)acc2[c][reg];
    __syncthreads();

    long gi = (long)blockIdx.x * 16 + (t >> 4);
    if (gi < n) {
        uint4 v = *(const uint4*)&Oh[t * 8];
        *(uint4*)&hOut[gi * 128 + (size_t)(t & 15) * 8] = v;
    }
}

// ---------------- final aggregation (fp32 out) ----------------

__global__ __launch_bounds__(256) void agg_final(const h8v* __restrict__ hH,
                                                 const float* __restrict__ dinv,
                                                 const int* __restrict__ row,
                                                 const int* __restrict__ esrc,
                                                 const float* __restrict__ bias,
                                                 float* __restrict__ out, int n) {
    int g    = threadIdx.x >> 4;
    int lane = threadIdx.x & 15;
    int i = blockIdx.x * 16 + g;
    if (i >= n) return;

    float di = dinv[i];
    float s2 = di * di;

    h8v self = hH[(size_t)i * 16 + lane];
    float acc[8];
#pragma unroll
    for (int k = 0; k < 8; k++) acc[k] = (float)self[k] * s2;

    int e0 = row[i], e1 = row[i + 1];
    int e = e0;
    for (; e + 4 <= e1; e += 4) {
        int s0 = esrc[e + 0];
        int s1 = esrc[e + 1];
        int s2i = esrc[e + 2];
        int s3 = esrc[e + 3];
        h8v v0 = hH[(size_t)s0 * 16 + lane];
        h8v v1 = hH[(size_t)s1 * 16 + lane];
        h8v v2 = hH[(size_t)s2i * 16 + lane];
        h8v v3 = hH[(size_t)s3 * 16 + lane];
        float w0 = dinv[s0] * di;
        float w1 = dinv[s1] * di;
        float w2 = dinv[s2i] * di;
        float w3 = dinv[s3] * di;
#pragma unroll
        for (int k = 0; k < 8; k++)
            acc[k] += w0 * (float)v0[k] + w1 * (float)v1[k] + w2 * (float)v2[k] + w3 * (float)v3[k];
    }
    for (; e < e1; ++e) {
        int s = esrc[e];
        h8v v = hH[(size_t)s * 16 + lane];
        float w = dinv[s] * di;
#pragma unroll
        for (int k = 0; k < 8; k++) acc[k] += w * (float)v[k];
    }

    const float4* b4 = (const float4*)(bias + lane * 8);
    float4 bA = b4[0], bB = b4[1];
    float4* o4 = (float4*)(out + (size_t)i * 128 + lane * 8);
    o4[0] = make_float4(fmaxf(acc[0] + bA.x, 0.f), fmaxf(acc[1] + bA.y, 0.f),
                        fmaxf(acc[2] + bA.z, 0.f), fmaxf(acc[3] + bA.w, 0.f));
    o4[1] = make_float4(fmaxf(acc[4] + bB.x, 0.f), fmaxf(acc[5] + bB.y, 0.f),
                        fmaxf(acc[6] + bB.z, 0.f), fmaxf(acc[7] + bB.w, 0.f));
}

// ---------------- launch ----------------

extern "C" void kernel_launch(void* const* d_in, const int* in_sizes, int n_in,
                              void* d_out, int out_size, void* d_ws, size_t ws_size,
                              hipStream_t stream) {
    const float* x  = (const float*)d_in[0];
    const int*   ei = (const int*)d_in[1];
    const float* W0 = (const float*)d_in[2];
    const float* b0 = (const float*)d_in[3];
    const float* W1 = (const float*)d_in[4];
    const float* b1 = (const float*)d_in[5];
    const float* W2 = (const float*)d_in[6];
    const float* b2 = (const float*)d_in[7];

    const int H = 128;
    int n = in_sizes[0] / H;
    int E = in_sizes[1] / 2;
    const int* srcp = ei;
    const int* dstp = ei + E;

    int gemm_blocks = (n + 127) / 128;
    long npad = (long)gemm_blocks * 128;
    int nbuck = (n + BSPAN - 1) >> BSHIFT;   // <= PB for n <= 131072

    char* p = (char*)d_ws;
    auto alloc = [&](size_t bytes) {
        void* r = (void*)p;
        p += (bytes + 255) & ~(size_t)255;
        return r;
    };
    _Float16* bufH0 = (_Float16*)alloc((size_t)npad * H * 2);               // 25.6 MB
    _Float16* bufH1 = (_Float16*)alloc((size_t)npad * H * 2);               // 25.6 MB
    unsigned short* Whs = (unsigned short*)alloc(3 * 16384 * 2);
    unsigned short* Wls = (unsigned short*)alloc(3 * 16384 * 2);
    float* dinv  = (float*)alloc((size_t)n * sizeof(float));
    int*  row    = (int*)alloc((size_t)(n + 1) * sizeof(int));
    int*  bsize  = (int*)alloc(PB * sizeof(int));
    int*  bbase  = (int*)alloc((PB + 1) * sizeof(int));
    int*  bcursor= (int*)alloc(PB * sizeof(int));
    int2* part   = (int2*)alloc((size_t)E * sizeof(int2));                  // 12.8 MB
    int*  esrc   = (int*)alloc((size_t)E * sizeof(int));                    // 6.4 MB

    hipMemsetAsync(bsize, 0, PB * sizeof(int), stream);

    bhist_kernel<<<1024, 256, 0, stream>>>(dstp, E, bsize);
    bscan_kernel<<<1, PB, 0, stream>>>(bsize, bbase, bcursor, row, n, E);
    partition_kernel<<<(E + PCHUNK - 1) / PCHUNK, 256, 0, stream>>>(srcp, dstp, E, bcursor, part);
    csr_kernel<<<nbuck, 1024, 0, stream>>>(part, bbase, row, dinv, esrc, n);

    wsplit_kernel<<<(3 * 16384 + TPB - 1) / TPB, TPB, 0, stream>>>(W0, W1, W2, Whs, Wls);

    float* out = (float*)d_out;
    int node_blocks = (n + 15) / 16;

    // layer 0 linear: x @ W0 -> bufH0 (fp16)
    gemm0_mfma<<<gemm_blocks, 256, 0, stream>>>(x, Whs, Wls, bufH0, n);
    // fused: relu(agg(bufH0)+b0) @ W1 -> bufH1
    fused_kernel<<<node_blocks, 256, 0, stream>>>((const h8v*)bufH0, dinv, row, esrc, b0,
                                                  Whs + 16384, Wls + 16384, bufH1, n);
    // fused: relu(agg(bufH1)+b1) @ W2 -> bufH0
    fused_kernel<<<node_blocks, 256, 0, stream>>>((const h8v*)bufH1, dinv, row, esrc, b1,
                                                  Whs + 32768, Wls + 32768, bufH0, n);
    // final: relu(agg(bufH0)+b2) -> out (fp32)
    agg_final<<<node_blocks, 256, 0, stream>>>((const h8v*)bufH0, dinv, row, esrc, b2, out, n);
}

// Round 9
// 404.236 us; speedup vs baseline: 2.7726x; 1.0129x over previous
//
#include <hip/hip_runtime.h>
#include <hip/hip_bf16.h>

#define TPB 256

typedef short s8v __attribute__((ext_vector_type(8)));     // 8 bf16 in 4 VGPRs
typedef float f4v __attribute__((ext_vector_type(4)));
typedef _Float16 h8v __attribute__((ext_vector_type(8)));  // 8 fp16 in 4 VGPRs

#define PB 128         // buckets
#define BSHIFT 10
#define BSPAN 1024     // nodes per bucket
#define PCHUNK 4096    // edges per partition block
#define WBLK 192       // wsplit blocks (3*16384/256)

// ---- fp32 -> bf16 split helpers (RNE) ----
__device__ __forceinline__ unsigned short bf16_rne(float v) {
    unsigned int u = __float_as_uint(v);
    u += 0x7fffu + ((u >> 16) & 1u);
    return (unsigned short)(u >> 16);
}
__device__ __forceinline__ void split_bf16(float v, unsigned short& hi, unsigned short& lo) {
    hi = bf16_rne(v);
    float hf = __uint_as_float((unsigned int)hi << 16);
    lo = bf16_rne(v - hf);
}

// ---------------- bhist + wsplit (merged) ----------------
// blocks [0,WBLK): split+swizzle W. blocks [WBLK, WBLK+1024): dst bucket histogram.

__global__ __launch_bounds__(256) void bhist_wsplit_kernel(const int* __restrict__ dst, int E,
                                                           int* __restrict__ bsize,
                                                           const float* __restrict__ W0,
                                                           const float* __restrict__ W1,
                                                           const float* __restrict__ W2,
                                                           unsigned short* __restrict__ Whi,
                                                           unsigned short* __restrict__ Wlo) {
    __shared__ int h[PB];
    int t = threadIdx.x;
    if (blockIdx.x < WBLK) {
        int idx0 = blockIdx.x * 256 + t;            // 0 .. 3*16384
        if (idx0 < 3 * 16384) {
            int layer = idx0 >> 14;
            int e = idx0 & 16383;
            int k = e >> 7, ncol = e & 127;
            const float* W = (layer == 0) ? W0 : (layer == 1) ? W1 : W2;
            unsigned short hi, lo;
            split_bf16(W[e], hi, lo);
            int ct = ncol >> 4;
            int lane = (((k >> 3) & 3) << 4) | (ncol & 15);
            int kki = k >> 5;
            int j = k & 7;
            int oidx = layer * 16384 + (((ct * 4 + kki) * 64 + lane) * 8 + j);
            Whi[oidx] = hi; Wlo[oidx] = lo;
        }
        return;
    }
    int blk = blockIdx.x - WBLK;
    int nblk = gridDim.x - WBLK;
    if (t < PB) h[t] = 0;
    __syncthreads();
    for (int e = blk * 256 + t; e < E; e += nblk * 256)
        atomicAdd(&h[dst[e] >> BSHIFT], 1);
    __syncthreads();
    if (t < PB && h[t] > 0) atomicAdd(&bsize[t], h[t]);
}

__global__ void bscan_kernel(const int* __restrict__ bsize, int* __restrict__ bbase,
                             int* __restrict__ bcursor, int* __restrict__ row, int n, int E) {
    __shared__ int wtot[2];
    int t = threadIdx.x;            // 0..127
    int sz = bsize[t];
    int lane = t & 63, wid = t >> 6;
    int v = sz;
    for (int off = 1; off < 64; off <<= 1) {
        int u = __shfl_up(v, off);
        if (lane >= off) v += u;
    }
    if (lane == 63) wtot[wid] = v;
    __syncthreads();
    if (wid == 1) v += wtot[0];
    bbase[t + 1] = v;               // inclusive
    bcursor[t] = v - sz;            // exclusive
    if (t == 0) { bbase[0] = 0; row[n] = E; }
}

__global__ __launch_bounds__(256) void partition_kernel(const int* __restrict__ src,
                                                        const int* __restrict__ dst, int E,
                                                        int* __restrict__ bcursor,
                                                        int2* __restrict__ part) {
    __shared__ int h[PB];
    __shared__ int gofs[PB];
    int t = threadIdx.x;
    long base = (long)blockIdx.x * PCHUNK;
    int cnt = (int)min((long)PCHUNK, (long)E - base);

    if (t < PB) h[t] = 0;
    __syncthreads();
    for (int j = t; j < cnt; j += 256)
        atomicAdd(&h[dst[base + j] >> BSHIFT], 1);
    __syncthreads();
    if (t < PB) gofs[t] = (h[t] > 0) ? atomicAdd(&bcursor[t], h[t]) : 0;
    __syncthreads();
    if (t < PB) h[t] = 0;           // reuse as local cursor
    __syncthreads();
    for (int j = t; j < cnt; j += 256) {
        int s = src[base + j], d = dst[base + j];   // re-read: L2-hot
        int b = d >> BSHIFT;
        int idx = atomicAdd(&h[b], 1);
        part[(long)gofs[b] + idx] = make_int2(s, d);
    }
}

__global__ __launch_bounds__(1024) void csr_kernel(const int2* __restrict__ part,
                                                   const int* __restrict__ bbase,
                                                   int* __restrict__ row, float* __restrict__ dinv,
                                                   int* __restrict__ esrc, int n) {
    __shared__ int deg[BSPAN];
    __shared__ int lrow[BSPAN];
    __shared__ int cur[BSPAN];
    __shared__ int wsum[16];
    int b = blockIdx.x;
    int n0 = b << BSHIFT;
    int nn = min(BSPAN, n - n0);
    if (nn <= 0) return;
    int e0 = bbase[b], e1 = bbase[b + 1];
    int t = threadIdx.x;

    deg[t] = 0;
    __syncthreads();
    for (int e = e0 + t; e < e1; e += 1024)
        atomicAdd(&deg[part[e].y - n0], 1);
    __syncthreads();

    int a = deg[t];
    int lane = t & 63, wid = t >> 6;
    int v = a;
    for (int off = 1; off < 64; off <<= 1) {
        int u = __shfl_up(v, off);
        if (lane >= off) v += u;
    }
    if (lane == 63) wsum[wid] = v;
    __syncthreads();
    if (wid == 0 && lane < 16) {
        int w = wsum[lane];
        for (int off = 1; off < 16; off <<= 1) {
            int u = __shfl_up(w, off);
            if (lane >= off) w += u;
        }
        wsum[lane] = w;
    }
    __syncthreads();
    int excl = v - a + ((wid > 0) ? wsum[wid - 1] : 0);
    lrow[t] = excl;
    cur[t] = 0;
    if (t < nn) {
        row[n0 + t] = e0 + excl;
        dinv[n0 + t] = rsqrtf((float)(deg[t] + 1));
    }
    __syncthreads();

    for (int e = e0 + t; e < e1; e += 1024) {
        int2 p = part[e];
        int d = p.y - n0;
        int idx = atomicAdd(&cur[d], 1);
        esrc[e0 + lrow[d] + idx] = p.x;
    }
}

// ---------------- layer-0 GEMM: h0 = x @ W0 (fp16 out) ----------------
// B-frags loaded per k-step (L2-hot W) -> ~96 fewer live VGPRs than hoisted form.
// LDS out-stage stride 136 halfwords (272B rows: 16B-aligned, 4-way banks not 8).

__global__ __launch_bounds__(256, 3) void gemm0_mfma(const float* __restrict__ Xf,
                                                     const unsigned short* __restrict__ Whs,
                                                     const unsigned short* __restrict__ Wls,
                                                     _Float16* __restrict__ Ch, int n) {
    __shared__ _Float16 Oh[128 * 136];
    int t = threadIdx.x;
    int wave = t >> 6, lane = t & 63;
    int ch = wave & 1, rh = wave >> 1;
    int lm = lane & 15, q = lane >> 4;
    long row0 = (long)blockIdx.x * 128 + rh * 64;

    const s8v* Wh8 = (const s8v*)Whs;
    const s8v* Wl8 = (const s8v*)Wls;

    f4v acc[4][4];
#pragma unroll
    for (int rt = 0; rt < 4; rt++)
#pragma unroll
        for (int ct = 0; ct < 4; ct++) acc[rt][ct] = (f4v)0.0f;

#pragma unroll
    for (int kki = 0; kki < 4; kki++) {
        s8v bh[4], bl[4];
#pragma unroll
        for (int ct = 0; ct < 4; ct++) {
            int idx = (((ch * 4 + ct) * 4 + kki) * 64) + lane;
            bh[ct] = Wh8[idx];
            bl[ct] = Wl8[idx];
        }
        s8v ah[4], al[4];
#pragma unroll
        for (int rt = 0; rt < 4; rt++) {
            long r = row0 + rt * 16 + lm;
            long rr = (r < n) ? r : (n - 1);   // clamp: padded rows discarded
            const float4* xf4 = (const float4*)(Xf + rr * 128 + kki * 32 + q * 8);
            float4 u0 = xf4[0], u1 = xf4[1];
            float uf[8] = {u0.x, u0.y, u0.z, u0.w, u1.x, u1.y, u1.z, u1.w};
            s8v hv, lv;
#pragma unroll
            for (int j = 0; j < 8; j++) {
                unsigned short hh, ll;
                split_bf16(uf[j], hh, ll);
                hv[j] = (short)hh; lv[j] = (short)ll;
            }
            ah[rt] = hv; al[rt] = lv;
        }
#pragma unroll
        for (int rt = 0; rt < 4; rt++)
#pragma unroll
            for (int ct = 0; ct < 4; ct++) {
                acc[rt][ct] = __builtin_amdgcn_mfma_f32_16x16x32_bf16(ah[rt], bh[ct], acc[rt][ct], 0, 0, 0);
                acc[rt][ct] = __builtin_amdgcn_mfma_f32_16x16x32_bf16(ah[rt], bl[ct], acc[rt][ct], 0, 0, 0);
                acc[rt][ct] = __builtin_amdgcn_mfma_f32_16x16x32_bf16(al[rt], bh[ct], acc[rt][ct], 0, 0, 0);
            }
    }

    // stage fp16 tile in LDS (stride 136), then coalesced 16B stores
#pragma unroll
    for (int rt = 0; rt < 4; rt++)
#pragma unroll
        for (int reg = 0; reg < 4; reg++) {
            int lr = rh * 64 + rt * 16 + q * 4 + reg;
#pragma unroll
            for (int ct = 0; ct < 4; ct++)
                Oh[lr * 136 + ch * 64 + ct * 16 + lm] = (_Float16)acc[rt][ct][reg];
        }
    __syncthreads();

    long rowb = (long)blockIdx.x * 128;
    int lr = t >> 1;                    // local row
    int cb = (t & 1) * 64;              // col base: 64 halves = 8 uint4 per thread
    if (rowb + lr < n) {
        const uint4* s = (const uint4*)&Oh[lr * 136 + cb];
        uint4* d = (uint4*)&Ch[(rowb + lr) * 128 + cb];
#pragma unroll
        for (int u = 0; u < 8; u++) d[u] = s[u];
    }
}

// ---------------- fused agg + next-layer GEMM ----------------
// r = relu( sum_e dinv[s]*di*hIn[s] + di^2*hIn[i] + b );  hOut = fp16( r @ Wnext )
// 256 thr = 16 nodes; gather: 16 lanes/node x 8 feats. GEMM: 16x128 @ 128x128 via MFMA.

__global__ __launch_bounds__(256) void fused_kernel(const h8v* __restrict__ hIn,
                                                    const float* __restrict__ dinv,
                                                    const int* __restrict__ row,
                                                    const int* __restrict__ esrc,
                                                    const float* __restrict__ bias,
                                                    const unsigned short* __restrict__ Whs,
                                                    const unsigned short* __restrict__ Wls,
                                                    _Float16* __restrict__ hOut, int n) {
    __shared__ float As[16 * 132];   // padded stride 132; reused as fp16 out-stage (stride 136)
    int t = threadIdx.x;
    int g = t >> 4, lane = t & 15;
    long i = (long)blockIdx.x * 16 + g;

    float r[8];
    if (i < n) {
        float di = dinv[i];
        float s2 = di * di;
        h8v self = hIn[i * 16 + lane];
        float acc[8];
#pragma unroll
        for (int k = 0; k < 8; k++) acc[k] = (float)self[k] * s2;

        int e0 = row[i], e1 = row[i + 1];
        int e = e0;
        for (; e + 4 <= e1; e += 4) {
            int s0 = esrc[e + 0];
            int s1 = esrc[e + 1];
            int s2i = esrc[e + 2];
            int s3 = esrc[e + 3];
            h8v v0 = hIn[(size_t)s0 * 16 + lane];
            h8v v1 = hIn[(size_t)s1 * 16 + lane];
            h8v v2 = hIn[(size_t)s2i * 16 + lane];
            h8v v3 = hIn[(size_t)s3 * 16 + lane];
            float w0 = dinv[s0] * di;
            float w1 = dinv[s1] * di;
            float w2 = dinv[s2i] * di;
            float w3 = dinv[s3] * di;
#pragma unroll
            for (int k = 0; k < 8; k++)
                acc[k] += w0 * (float)v0[k] + w1 * (float)v1[k] + w2 * (float)v2[k] + w3 * (float)v3[k];
        }
        for (; e < e1; ++e) {
            int s = esrc[e];
            h8v v = hIn[(size_t)s * 16 + lane];
            float w = dinv[s] * di;
#pragma unroll
            for (int k = 0; k < 8; k++) acc[k] += w * (float)v[k];
        }

        const float4* b4 = (const float4*)(bias + lane * 8);
        float4 bA = b4[0], bB = b4[1];
        r[0] = fmaxf(acc[0] + bA.x, 0.f); r[1] = fmaxf(acc[1] + bA.y, 0.f);
        r[2] = fmaxf(acc[2] + bA.z, 0.f); r[3] = fmaxf(acc[3] + bA.w, 0.f);
        r[4] = fmaxf(acc[4] + bB.x, 0.f); r[5] = fmaxf(acc[5] + bB.y, 0.f);
        r[6] = fmaxf(acc[6] + bB.z, 0.f); r[7] = fmaxf(acc[7] + bB.w, 0.f);
    } else {
#pragma unroll
        for (int k = 0; k < 8; k++) r[k] = 0.f;
    }

    float* dstA = &As[g * 132 + lane * 8];
    *(float4*)dstA = make_float4(r[0], r[1], r[2], r[3]);
    *(float4*)(dstA + 4) = make_float4(r[4], r[5], r[6], r[7]);
    __syncthreads();

    // GEMM phase: wave w handles cols [w*32, w*32+32)
    int w = t >> 6, l64 = t & 63;
    int lm = l64 & 15, q = l64 >> 4;

    const s8v* Wh8 = (const s8v*)Whs;
    const s8v* Wl8 = (const s8v*)Wls;
    s8v Bh[2][4], Bl[2][4];
#pragma unroll
    for (int c = 0; c < 2; c++)
#pragma unroll
        for (int kki = 0; kki < 4; kki++) {
            int idx = (((w * 2 + c) * 4 + kki) * 64) + l64;
            Bh[c][kki] = Wh8[idx];
            Bl[c][kki] = Wl8[idx];
        }

    f4v acc2[2];
    acc2[0] = (f4v)0.0f; acc2[1] = (f4v)0.0f;

#pragma unroll
    for (int kki = 0; kki < 4; kki++) {
        const float* ap = &As[lm * 132 + kki * 32 + q * 8];
        float4 u0 = *(const float4*)ap;
        float4 u1 = *(const float4*)(ap + 4);
        float uf[8] = {u0.x, u0.y, u0.z, u0.w, u1.x, u1.y, u1.z, u1.w};
        s8v hv, lv;
#pragma unroll
        for (int j = 0; j < 8; j++) {
            unsigned short hh, ll;
            split_bf16(uf[j], hh, ll);
            hv[j] = (short)hh; lv[j] = (short)ll;
        }
#pragma unroll
        for (int c = 0; c < 2; c++) {
            acc2[c] = __builtin_amdgcn_mfma_f32_16x16x32_bf16(hv, Bh[c][kki], acc2[c], 0, 0, 0);
            acc2[c] = __builtin_amdgcn_mfma_f32_16x16x32_bf16(hv, Bl[c][kki], acc2[c], 0, 0, 0);
            acc2[c] = __builtin_amdgcn_mfma_f32_16x16x32_bf16(lv, Bh[c][kki], acc2[c], 0, 0, 0);
        }
    }
    __syncthreads();

    _Float16* Oh = (_Float16*)As;     // stride 136 halves (272B rows: 16B-aligned, bank-spread)
#pragma unroll
    for (int c = 0; c < 2; c++)
#pragma unroll
        for (int reg = 0; reg < 4; reg++)
            Oh[(q * 4 + reg) * 136 + (w * 2 + c) * 16 + lm] = (_Float16)acc2[c][reg];
    __syncthreads();

    long gi = (long)blockIdx.x * 16 + (t >> 4);
    if (gi < n) {
        uint4 v = *(const uint4*)&Oh[(t >> 4) * 136 + (t & 15) * 8];
        *(uint4*)&hOut[gi * 128 + (size_t)(t & 15) * 8] = v;
    }
}

// ---------------- final aggregation (fp32 out) ----------------

__global__ __launch_bounds__(256) void agg_final(const h8v* __restrict__ hH,
                                                 const float* __restrict__ dinv,
                                                 const int* __restrict__ row,
                                                 const int* __restrict__ esrc,
                                                 const float* __restrict__ bias,
                                                 float* __restrict__ out, int n) {
    int g    = threadIdx.x >> 4;
    int lane = threadIdx.x & 15;
    int i = blockIdx.x * 16 + g;
    if (i >= n) return;

    float di = dinv[i];
    float s2 = di * di;

    h8v self = hH[(size_t)i * 16 + lane];
    float acc[8];
#pragma unroll
    for (int k = 0; k < 8; k++) acc[k] = (float)self[k] * s2;

    int e0 = row[i], e1 = row[i + 1];
    int e = e0;
    for (; e + 4 <= e1; e += 4) {
        int s0 = esrc[e + 0];
        int s1 = esrc[e + 1];
        int s2i = esrc[e + 2];
        int s3 = esrc[e + 3];
        h8v v0 = hH[(size_t)s0 * 16 + lane];
        h8v v1 = hH[(size_t)s1 * 16 + lane];
        h8v v2 = hH[(size_t)s2i * 16 + lane];
        h8v v3 = hH[(size_t)s3 * 16 + lane];
        float w0 = dinv[s0] * di;
        float w1 = dinv[s1] * di;
        float w2 = dinv[s2i] * di;
        float w3 = dinv[s3] * di;
#pragma unroll
        for (int k = 0; k < 8; k++)
            acc[k] += w0 * (float)v0[k] + w1 * (float)v1[k] + w2 * (float)v2[k] + w3 * (float)v3[k];
    }
    for (; e < e1; ++e) {
        int s = esrc[e];
        h8v v = hH[(size_t)s * 16 + lane];
        float w = dinv[s] * di;
#pragma unroll
        for (int k = 0; k < 8; k++) acc[k] += w * (float)v[k];
    }

    const float4* b4 = (const float4*)(bias + lane * 8);
    float4 bA = b4[0], bB = b4[1];
    float4* o4 = (float4*)(out + (size_t)i * 128 + lane * 8);
    o4[0] = make_float4(fmaxf(acc[0] + bA.x, 0.f), fmaxf(acc[1] + bA.y, 0.f),
                        fmaxf(acc[2] + bA.z, 0.f), fmaxf(acc[3] + bA.w, 0.f));
    o4[1] = make_float4(fmaxf(acc[4] + bB.x, 0.f), fmaxf(acc[5] + bB.y, 0.f),
                        fmaxf(acc[6] + bB.z, 0.f), fmaxf(acc[7] + bB.w, 0.f));
}

// ---------------- launch ----------------

extern "C" void kernel_launch(void* const* d_in, const int* in_sizes, int n_in,
                              void* d_out, int out_size, void* d_ws, size_t ws_size,
                              hipStream_t stream) {
    const float* x  = (const float*)d_in[0];
    const int*   ei = (const int*)d_in[1];
    const float* W0 = (const float*)d_in[2];
    const float* b0 = (const float*)d_in[3];
    const float* W1 = (const float*)d_in[4];
    const float* b1 = (const float*)d_in[5];
    const float* W2 = (const float*)d_in[6];
    const float* b2 = (const float*)d_in[7];

    const int H = 128;
    int n = in_sizes[0] / H;
    int E = in_sizes[1] / 2;
    const int* srcp = ei;
    const int* dstp = ei + E;

    int gemm_blocks = (n + 127) / 128;
    long npad = (long)gemm_blocks * 128;
    int nbuck = (n + BSPAN - 1) >> BSHIFT;   // <= PB for n <= 131072

    char* p = (char*)d_ws;
    auto alloc = [&](size_t bytes) {
        void* r = (void*)p;
        p += (bytes + 255) & ~(size_t)255;
        return r;
    };
    _Float16* bufH0 = (_Float16*)alloc((size_t)npad * H * 2);               // 25.6 MB
    _Float16* bufH1 = (_Float16*)alloc((size_t)npad * H * 2);               // 25.6 MB
    unsigned short* Whs = (unsigned short*)alloc(3 * 16384 * 2);
    unsigned short* Wls = (unsigned short*)alloc(3 * 16384 * 2);
    float* dinv  = (float*)alloc((size_t)n * sizeof(float));
    int*  row    = (int*)alloc((size_t)(n + 1) * sizeof(int));
    int*  bsize  = (int*)alloc(PB * sizeof(int));
    int*  bbase  = (int*)alloc((PB + 1) * sizeof(int));
    int*  bcursor= (int*)alloc(PB * sizeof(int));
    int2* part   = (int2*)alloc((size_t)E * sizeof(int2));                  // 12.8 MB
    int*  esrc   = (int*)alloc((size_t)E * sizeof(int));                    // 6.4 MB

    hipMemsetAsync(bsize, 0, PB * sizeof(int), stream);

    bhist_wsplit_kernel<<<WBLK + 1024, 256, 0, stream>>>(dstp, E, bsize, W0, W1, W2, Whs, Wls);
    bscan_kernel<<<1, PB, 0, stream>>>(bsize, bbase, bcursor, row, n, E);
    partition_kernel<<<(E + PCHUNK - 1) / PCHUNK, 256, 0, stream>>>(srcp, dstp, E, bcursor, part);
    csr_kernel<<<nbuck, 1024, 0, stream>>>(part, bbase, row, dinv, esrc, n);

    float* out = (float*)d_out;
    int node_blocks = (n + 15) / 16;

    // layer 0 linear: x @ W0 -> bufH0 (fp16)
    gemm0_mfma<<<gemm_blocks, 256, 0, stream>>>(x, Whs, Wls, bufH0, n);
    // fused: relu(agg(bufH0)+b0) @ W1 -> bufH1
    fused_kernel<<<node_blocks, 256, 0, stream>>>((const h8v*)bufH0, dinv, row, esrc, b0,
                                                  Whs + 16384, Wls + 16384, bufH1, n);
    // fused: relu(agg(bufH1)+b1) @ W2 -> bufH0
    fused_kernel<<<node_blocks, 256, 0, stream>>>((const h8v*)bufH1, dinv, row, esrc, b1,
                                                  Whs + 32768, Wls + 32768, bufH0, n);
    // final: relu(agg(bufH0)+b2) -> out (fp32)
    agg_final<<<node_blocks, 256, 0, stream>>>((const h8v*)bufH0, dinv, row, esrc, b2, out, n);
}